// Round 1
// baseline (552.906 us; speedup 1.0000x reference)
//
#include <hip/hip_runtime.h>

#define DI __device__ __forceinline__

typedef __attribute__((ext_vector_type(8))) __bf16 bf16x8;
typedef __attribute__((ext_vector_type(4))) float f32x4;

DI unsigned short f2bf(float x) {
  union { float f; unsigned u; } v; v.f = x;
  unsigned r = v.u + 0x7fffu + ((v.u >> 16) & 1u);
  return (unsigned short)(r >> 16);
}
DI float bf2f(unsigned short h) {
  union { unsigned u; float f; } v; v.u = ((unsigned)h) << 16;
  return v.f;
}
DI unsigned pack2(float a, float b) {
  return (unsigned)f2bf(a) | (((unsigned)f2bf(b)) << 16);
}

// Async global->LDS DMA, 16B per lane. LDS dest is wave-uniform base +
// lane*16 (HW scatter); global src is per-lane. Drained by the implicit
// vmcnt(0) the compiler emits before s_barrier (__syncthreads).
DI void gl_lds16(const void* g, void* l) {
  __builtin_amdgcn_global_load_lds(
      (const __attribute__((address_space(1))) void*)g,
      (__attribute__((address_space(3))) void*)l, 16, 0, 0);
}

// ---------------------------------------------------------------------------
// P0: transpose-convert [b][512 c][4096 n] f32 -> [b][4096 n][512 c] bf16.
// 64x64 tiles via LDS (stride 65: verified conflict-free both sides).
// ---------------------------------------------------------------------------
__global__ __launch_bounds__(256) void p0_transpose(
    const float* __restrict__ src, unsigned short* __restrict__ dst)
{
  const int n0 = blockIdx.x * 64, c0 = blockIdx.y * 64, b = blockIdx.z;
  const int tid = threadIdx.x;
  __shared__ float T[64 * 65];
  #pragma unroll
  for (int p = 0; p < 4; ++p) {
    int r = p * 16 + (tid >> 4);
    int n4 = (tid & 15) << 2;
    *(float4*)&T[r * 65 + n4] =
        *(const float4*)(src + ((size_t)(b * 512 + c0 + r)) * 4096 + n0 + n4);
  }
  __syncthreads();
  int n = tid >> 2, cc = (tid & 3) * 16;
  unsigned u[8];
  #pragma unroll
  for (int j = 0; j < 16; j += 2)
    u[j >> 1] = pack2(T[(cc + j) * 65 + n], T[(cc + j + 1) * 65 + n]);
  unsigned short* d = dst + ((size_t)(b * 4096 + n0 + n)) * 512 + c0 + cc;
  *(uint4*)(d) = make_uint4(u[0], u[1], u[2], u[3]);
  *(uint4*)(d + 8) = make_uint4(u[4], u[5], u[6], u[7]);
}

// ---------------------------------------------------------------------------
// K1F: conv (theta|g) for a 128o x 128n tile via bf16 MFMA from pre-transposed
// yT, then fused SPP w-bin pooling epilogue -> Rbuf[b][64 h][18 wbin][512 ch].
// This round: B operand staged via global_load_lds (linear [128][32] LDS —
// 16B-position spread is even, same as the old pad-40), A stays reg-staged
// (needs fp32->bf16 convert, which now overlaps the B DMA). Grid flattened to
// (128 tiles, 16 b) with XCD-chunked swizzle so the 4 mb-blocks sharing one
// yT B-tile land on the same XCD (L2 reuse).
// ---------------------------------------------------------------------------
__constant__ int c_RS[18] = {0, 0,21,42, 0,10,21,32,42,53, 0,8,16,24,32,40,48,56};
__constant__ int c_RE[18] = {64, 22,43,64, 11,22,32,43,54,64, 8,16,24,32,40,48,56,64};

__global__ __launch_bounds__(256) void k1f_conv_pool(
    const unsigned short* __restrict__ yT, const float* __restrict__ w_theta,
    const float* __restrict__ w_g, unsigned short* __restrict__ Rbuf)
{
  const int tid = threadIdx.x;
  const int id = blockIdx.x;                    // 0..127 tiles within batch
  const int tile = (id & 7) * 16 + (id >> 3);   // XCD-chunked, bijective (128%8==0)
  const int mb = (tile & 3) * 128;              // output-channel tile (theta|g)
  const int nbt = tile >> 2;                    // spatial tile index (0..31)
  const int nb = nbt * 128;
  const int b  = blockIdx.y;
  const int lane = tid & 63, wv = tid >> 6;
  const int wm = (wv & 1) * 64, wn = (wv >> 1) * 64;
  const int l15 = lane & 15, l4 = lane >> 4;

  __shared__ __align__(16) char smem[33280];    // union: staging 16KB | epi 33.3KB
  unsigned short* As = (unsigned short*)smem;            // [128][32] bf16, 8KB
  unsigned short* Bs = (unsigned short*)(smem + 8192);   // [128][32] bf16, 8KB
  float* P = (float*)smem;

  f32x4 acc[4][4];
  #pragma unroll
  for (int i = 0; i < 4; ++i)
    #pragma unroll
    for (int j = 0; j < 4; ++j) acc[i][j] = f32x4{0.f, 0.f, 0.f, 0.f};

  for (int kb = 0; kb < 512; kb += 32) {
    // B: yT -> LDS via async DMA (issued first; overlaps A convert below).
    #pragma unroll
    for (int p = 0; p < 2; ++p) {
      int chunk = (wv * 2 + p) * 64 + lane;     // 16B chunk id, 0..511
      int row = chunk >> 2, c16 = chunk & 3;
      gl_lds16(yT + ((size_t)(b * 4096 + nb + row)) * 512 + kb + c16 * 8,
               Bs + (wv * 2 + p) * 512);
    }
    // A: weights fp32 -> bf16 (linear [128][32]; b64 writes, even banks)
    #pragma unroll
    for (int j = 0; j < 4; ++j) {
      int flat = tid + 256 * j;
      int row = flat >> 3, c4 = (flat & 7) << 2;
      int og = mb + row;
      const float* wr = (og < 256) ? (w_theta + (size_t)og * 512)
                                   : (w_g + (size_t)(og - 256) * 512);
      float4 v = *(const float4*)(wr + kb + c4);
      uint2 u; u.x = pack2(v.x, v.y); u.y = pack2(v.z, v.w);
      *(uint2*)&As[row * 32 + c4] = u;
    }
    __syncthreads();
    bf16x8 af[4], bfr[4];
    #pragma unroll
    for (int i = 0; i < 4; ++i)
      af[i] = *(const bf16x8*)&As[(wm + i * 16 + l15) * 32 + l4 * 8];
    #pragma unroll
    for (int j = 0; j < 4; ++j)
      bfr[j] = *(const bf16x8*)&Bs[(wn + j * 16 + l15) * 32 + l4 * 8];
    #pragma unroll
    for (int i = 0; i < 4; ++i)
      #pragma unroll
      for (int j = 0; j < 4; ++j)
        acc[i][j] = __builtin_amdgcn_mfma_f32_16x16x32_bf16(af[i], bfr[j], acc[i][j], 0, 0, 0);
    __syncthreads();
  }

  // Fused pooling epilogue: two passes (n-halves = image rows h, h+1).
  const int hloc = wv >> 1;
  #pragma unroll
  for (int pass = 0; pass < 2; ++pass) {
    __syncthreads();
    if (hloc == pass) {
      #pragma unroll
      for (int i = 0; i < 4; ++i)
        #pragma unroll
        for (int j = 0; j < 4; ++j)
          #pragma unroll
          for (int r = 0; r < 4; ++r)
            P[(wm + i * 16 + l4 * 4 + r) * 65 + j * 16 + l15] = acc[i][j][r];
    }
    __syncthreads();
    const int o = tid & 127;
    size_t rbase = (((size_t)(b * 64 + nbt * 2 + pass)) * 18) * 512 + mb + o;
    if (tid < 128) {
      // levels 1 and 3 (w-bins 0..3)
      float b0 = -3.4e38f, b1 = b0, b2 = b0, b3 = b0;
      #pragma unroll
      for (int w = 0; w < 64; ++w) {
        float v = P[o * 65 + w];
        b0 = fmaxf(b0, v);
        if (w < 22) b1 = fmaxf(b1, v);
        if (w >= 21 && w < 43) b2 = fmaxf(b2, v);
        if (w >= 42) b3 = fmaxf(b3, v);
      }
      Rbuf[rbase]           = f2bf(b0);
      Rbuf[rbase + 512]     = f2bf(b1);
      Rbuf[rbase + 2 * 512] = f2bf(b2);
      Rbuf[rbase + 3 * 512] = f2bf(b3);
    } else {
      // levels 6 and 8 (w-bins 4..17)
      float s6[6], s8[8];
      #pragma unroll
      for (int i = 0; i < 6; ++i) s6[i] = -3.4e38f;
      #pragma unroll
      for (int i = 0; i < 8; ++i) s8[i] = -3.4e38f;
      constexpr int R6S[6] = {0, 10, 21, 32, 42, 53};
      constexpr int R6E[6] = {11, 22, 32, 43, 54, 64};
      #pragma unroll
      for (int w = 0; w < 64; ++w) {
        float v = P[o * 65 + w];
        #pragma unroll
        for (int i = 0; i < 6; ++i)
          if (w >= R6S[i] && w < R6E[i]) s6[i] = fmaxf(s6[i], v);
        s8[w >> 3] = fmaxf(s8[w >> 3], v);
      }
      #pragma unroll
      for (int i = 0; i < 6; ++i) Rbuf[rbase + (size_t)(4 + i) * 512] = f2bf(s6[i]);
      #pragma unroll
      for (int i = 0; i < 8; ++i) Rbuf[rbase + (size_t)(10 + i) * 512] = f2bf(s8[i]);
    }
  }
}

// ---------------------------------------------------------------------------
// K2F: reduce Rbuf over h within each pyramid h-bin -> Pt/Pg [b][128 s][256].
// Rows s >= 110 zeroed (required by downstream K/score/exp path).
// ---------------------------------------------------------------------------
__global__ __launch_bounds__(256) void k2_pool_final(
    const unsigned short* __restrict__ Rbuf, float* __restrict__ Pt,
    float* __restrict__ Pg)
{
  const int s = blockIdx.x, b = blockIdx.y, tid = threadIdx.x;
  size_t obase = ((size_t)(b * 128) + s) * 256 + tid;
  if (s >= 110) { Pt[obase] = 0.f; Pg[obase] = 0.f; return; }
  int he, wb;
  if (s == 0)      { he = 0; wb = 0; }
  else if (s < 10) { int i = s - 1;  he = 1 + i / 3;  wb = 1 + i % 3; }
  else if (s < 46) { int i = s - 10; he = 4 + i / 6;  wb = 4 + i % 6; }
  else             { int i = s - 46; he = 10 + i / 8; wb = 10 + i % 8; }
  float m0 = -3.4e38f, m1 = -3.4e38f;
  int e = c_RE[he];
  for (int h = c_RS[he]; h < e; ++h) {
    const unsigned short* r = Rbuf + (((size_t)(b * 64 + h)) * 18 + wb) * 512;
    m0 = fmaxf(m0, bf2f(r[tid]));
    m1 = fmaxf(m1, bf2f(r[tid + 256]));
  }
  Pt[obase] = m0;
  Pg[obase] = m1;
}

// ---------------------------------------------------------------------------
// K3a: Kt[b,s,c] = sum_ic w_phi[ic,c] * Pt[b,s,ic]  (fp32 VALU), split hi/lo.
// ---------------------------------------------------------------------------
__global__ __launch_bounds__(256) void k3_kmat(
    const float* __restrict__ Pt, const float* __restrict__ w_phi,
    unsigned short* __restrict__ Kth, unsigned short* __restrict__ Ktl)
{
  const int ct = blockIdx.x, b = blockIdx.y, tid = threadIdx.x;
  const int tx = tid & 15, ty = tid >> 4;
  const int c0 = tx * 4, s0 = ty * 8;
  __shared__ float Ls[128 * 64];
  __shared__ float Ws[64 * 68];
  float acc[8][4] = {};
  for (int kc = 0; kc < 256; kc += 64) {
    #pragma unroll
    for (int j = 0; j < 8; ++j) {
      int flat = tid + 256 * j;
      int row = flat >> 4, k4 = (flat & 15) << 2;
      *(float4*)&Ls[row * 64 + k4] =
          *(const float4*)(Pt + ((size_t)(b * 128) + row) * 256 + kc + k4);
    }
    #pragma unroll
    for (int j = 0; j < 4; ++j) {
      int flat = tid + 256 * j;
      int row = flat >> 4, c4 = (flat & 15) << 2;
      *(float4*)&Ws[row * 68 + c4] =
          *(const float4*)(w_phi + (size_t)(kc + row) * 512 + ct * 64 + c4);
    }
    __syncthreads();
    for (int k = 0; k < 64; k += 4) {
      float4 wv[4];
      #pragma unroll
      for (int kk = 0; kk < 4; ++kk) wv[kk] = *(const float4*)&Ws[(k + kk) * 68 + c0];
      #pragma unroll
      for (int i = 0; i < 8; ++i) {
        float4 a = *(const float4*)&Ls[(s0 + i) * 64 + k];
        const float* ap = (const float*)&a;
        #pragma unroll
        for (int kk = 0; kk < 4; ++kk) {
          const float* wp = (const float*)&wv[kk];
          acc[i][0] += ap[kk] * wp[0];
          acc[i][1] += ap[kk] * wp[1];
          acc[i][2] += ap[kk] * wp[2];
          acc[i][3] += ap[kk] * wp[3];
        }
      }
    }
    __syncthreads();
  }
  #pragma unroll
  for (int i = 0; i < 8; ++i) {
    unsigned short hi[4]; float lo[4];
    #pragma unroll
    for (int j = 0; j < 4; ++j) { hi[j] = f2bf(acc[i][j]); lo[j] = acc[i][j] - bf2f(hi[j]); }
    size_t base = ((size_t)(b * 128) + s0 + i) * 512 + ct * 64 + c0;
    uint2 uh; uh.x = (unsigned)hi[0] | ((unsigned)hi[1] << 16);
    uh.y = (unsigned)hi[2] | ((unsigned)hi[3] << 16);
    uint2 ul; ul.x = pack2(lo[0], lo[1]); ul.y = pack2(lo[2], lo[3]);
    *(uint2*)&Kth[base] = uh;
    *(uint2*)&Ktl[base] = ul;
  }
}

// ---------------------------------------------------------------------------
// K3b: V[b,o,s] = sum_ic w_mask[o,ic] * Pg[b,s,ic]  (fp32 VALU)
// ---------------------------------------------------------------------------
__global__ __launch_bounds__(256) void k3_vmat(
    const float* __restrict__ Pg, const float* __restrict__ w_mask,
    float* __restrict__ V)
{
  const int ot = blockIdx.x, b = blockIdx.y, tid = threadIdx.x;
  const int tx = tid & 15, ty = tid >> 4;
  const int o0 = ty * 4;
  __shared__ float Ws[64 * 64];
  __shared__ float Ps[128 * 68];
  float acc[4][8] = {};
  for (int kc = 0; kc < 256; kc += 64) {
    #pragma unroll
    for (int j = 0; j < 4; ++j) {
      int flat = tid + 256 * j;
      int row = flat >> 4, k4 = (flat & 15) << 2;
      *(float4*)&Ws[row * 64 + k4] =
          *(const float4*)(w_mask + (size_t)(ot * 64 + row) * 256 + kc + k4);
    }
    #pragma unroll
    for (int j = 0; j < 8; ++j) {
      int flat = tid + 256 * j;
      int row = flat >> 4, k4 = (flat & 15) << 2;
      *(float4*)&Ps[row * 68 + k4] =
          *(const float4*)(Pg + ((size_t)(b * 128) + row) * 256 + kc + k4);
    }
    __syncthreads();
    for (int k = 0; k < 64; k += 4) {
      float4 wv[4];
      #pragma unroll
      for (int i = 0; i < 4; ++i) wv[i] = *(const float4*)&Ws[(o0 + i) * 64 + k];
      #pragma unroll
      for (int jj = 0; jj < 8; ++jj) {
        float4 pv = *(const float4*)&Ps[(tx + 16 * jj) * 68 + k];
        const float* pp = (const float*)&pv;
        #pragma unroll
        for (int i = 0; i < 4; ++i) {
          const float* wp = (const float*)&wv[i];
          #pragma unroll
          for (int kk = 0; kk < 4; ++kk) acc[i][jj] += wp[kk] * pp[kk];
        }
      }
    }
    __syncthreads();
  }
  #pragma unroll
  for (int i = 0; i < 4; ++i)
    #pragma unroll
    for (int jj = 0; jj < 8; ++jj)
      V[((size_t)(b * 512) + ot * 64 + o0 + i) * 128 + tx + 16 * jj] = acc[i][jj];
}

// ---------------------------------------------------------------------------
// K4: scores[b,s,n] = sum_c Kt[b,s,c]*x[b,c,n]; Kt split hi/lo (2 MFMAs),
// x single-bf16 from pre-transposed xT. scores fp32 [B,128,N].
// This round: ALL THREE operand stages are straight bf16 copies -> staged via
// global_load_lds into linear [128][32] LDS (no VGPR round-trip, no padding).
// ---------------------------------------------------------------------------
__global__ __launch_bounds__(256) void k4_scores(
    const unsigned short* __restrict__ xT, const unsigned short* __restrict__ Kth,
    const unsigned short* __restrict__ Ktl, float* __restrict__ scores)
{
  const int tid = threadIdx.x;
  const int nb = blockIdx.x * 128;
  const int b = blockIdx.y;
  const int lane = tid & 63, wv = tid >> 6;
  const int wm = (wv & 1) * 64, wn = (wv >> 1) * 64;
  const int l15 = lane & 15, l4 = lane >> 4;
  __shared__ __align__(16) unsigned short Ah[128 * 32];
  __shared__ __align__(16) unsigned short Al[128 * 32];
  __shared__ __align__(16) unsigned short Bs[128 * 32];
  f32x4 acc[4][4];
  #pragma unroll
  for (int i = 0; i < 4; ++i)
    #pragma unroll
    for (int j = 0; j < 4; ++j) acc[i][j] = f32x4{0.f, 0.f, 0.f, 0.f};

  for (int kb = 0; kb < 512; kb += 32) {
    #pragma unroll
    for (int p = 0; p < 2; ++p) {
      int chunk = (wv * 2 + p) * 64 + lane;     // 16B chunk id, 0..511
      int row = chunk >> 2, c16 = chunk & 3;
      size_t g = ((size_t)(b * 128) + row) * 512 + kb + c16 * 8;
      gl_lds16(Kth + g, Ah + (wv * 2 + p) * 512);
      gl_lds16(Ktl + g, Al + (wv * 2 + p) * 512);
      gl_lds16(xT + ((size_t)(b * 4096 + nb + row)) * 512 + kb + c16 * 8,
               Bs + (wv * 2 + p) * 512);
    }
    __syncthreads();
    bf16x8 ah[4], al[4], bfr[4];
    #pragma unroll
    for (int i = 0; i < 4; ++i) {
      ah[i] = *(const bf16x8*)&Ah[(wm + i * 16 + l15) * 32 + l4 * 8];
      al[i] = *(const bf16x8*)&Al[(wm + i * 16 + l15) * 32 + l4 * 8];
    }
    #pragma unroll
    for (int j = 0; j < 4; ++j)
      bfr[j] = *(const bf16x8*)&Bs[(wn + j * 16 + l15) * 32 + l4 * 8];
    #pragma unroll
    for (int i = 0; i < 4; ++i)
      #pragma unroll
      for (int j = 0; j < 4; ++j) {
        acc[i][j] = __builtin_amdgcn_mfma_f32_16x16x32_bf16(ah[i], bfr[j], acc[i][j], 0, 0, 0);
        acc[i][j] = __builtin_amdgcn_mfma_f32_16x16x32_bf16(al[i], bfr[j], acc[i][j], 0, 0, 0);
      }
    __syncthreads();
  }
  #pragma unroll
  for (int i = 0; i < 4; ++i)
    #pragma unroll
    for (int j = 0; j < 4; ++j)
      #pragma unroll
      for (int r = 0; r < 4; ++r)
        scores[((size_t)(b * 128) + wm + i * 16 + l4 * 4 + r) * 4096 + nb + wn + j * 16 + l15] =
            acc[i][j][r];
}

// ---------------------------------------------------------------------------
// K5: per-(b,s) softmax stats over N=4096: m = max, linv = 1/sum(exp(v-m))
// ---------------------------------------------------------------------------
__global__ __launch_bounds__(256) void k5_stats(
    const float* __restrict__ scores, float* __restrict__ mbuf,
    float* __restrict__ lbuf)
{
  const int s = blockIdx.x, b = blockIdx.y, tid = threadIdx.x;
  if (s >= 110) {
    if (tid == 0) { mbuf[b * 128 + s] = 0.f; lbuf[b * 128 + s] = 0.f; }
    return;
  }
  const float* row = scores + ((size_t)(b * 128) + s) * 4096;
  float4 v[4];
  float m = -3.4e38f;
  #pragma unroll
  for (int j = 0; j < 4; ++j) {
    v[j] = *(const float4*)(row + (tid + 256 * j) * 4);
    m = fmaxf(m, fmaxf(fmaxf(v[j].x, v[j].y), fmaxf(v[j].z, v[j].w)));
  }
  #pragma unroll
  for (int off = 32; off > 0; off >>= 1) m = fmaxf(m, __shfl_down(m, off));
  __shared__ float red[8];
  if ((tid & 63) == 0) red[tid >> 6] = m;
  __syncthreads();
  float mm = fmaxf(fmaxf(red[0], red[1]), fmaxf(red[2], red[3]));
  float sum = 0.f;
  #pragma unroll
  for (int j = 0; j < 4; ++j)
    sum += __expf(v[j].x - mm) + __expf(v[j].y - mm) +
           __expf(v[j].z - mm) + __expf(v[j].w - mm);
  #pragma unroll
  for (int off = 32; off > 0; off >>= 1) sum += __shfl_down(sum, off);
  if ((tid & 63) == 0) red[4 + (tid >> 6)] = sum;
  __syncthreads();
  if (tid == 0) {
    float S = red[4] + red[5] + red[6] + red[7];
    mbuf[b * 128 + s] = mm;
    lbuf[b * 128 + s] = 1.f / S;
  }
}

// ---------------------------------------------------------------------------
// K5E: Eb[b,n,s] = bf16(exp(scores[b,s,n] - m[b,s]))  (transpose + exp)
// ---------------------------------------------------------------------------
__global__ __launch_bounds__(256) void k5e_expT(
    const float* __restrict__ scores, const float* __restrict__ mbuf,
    unsigned short* __restrict__ Eb)
{
  const int nt = blockIdx.x, b = blockIdx.y, tid = threadIdx.x;
  __shared__ float L[128 * 68];
  __shared__ float sm[128];
  if (tid < 128) sm[tid] = mbuf[b * 128 + tid];
  #pragma unroll
  for (int j = 0; j < 8; ++j) {
    int flat = tid + 256 * j;
    int s = flat >> 4, n4 = (flat & 15) << 2;
    *(float4*)&L[s * 68 + n4] =
        *(const float4*)(scores + ((size_t)(b * 128) + s) * 4096 + nt * 64 + n4);
  }
  __syncthreads();
  int n = tid >> 2, sq = (tid & 3) * 32;
  unsigned ub[16];
  #pragma unroll
  for (int k = 0; k < 32; k += 2) {
    float e0 = __expf(L[(sq + k) * 68 + n] - sm[sq + k]);
    float e1 = __expf(L[(sq + k + 1) * 68 + n] - sm[sq + k + 1]);
    ub[k >> 1] = pack2(e0, e1);
  }
  uint4* dst = (uint4*)(Eb + ((size_t)(b * 4096) + nt * 64 + n) * 128 + sq);
  #pragma unroll
  for (int j = 0; j < 4; ++j)
    dst[j] = make_uint4(ub[4 * j], ub[4 * j + 1], ub[4 * j + 2], ub[4 * j + 3]);
}

// ---------------------------------------------------------------------------
// K6: out[b,o,n] = sum_s (V[b,o,s]*linv[b,s]) * Eb[b,n,s] + x[b,o,n]
// ---------------------------------------------------------------------------
__global__ __launch_bounds__(256) void k6_out(
    const unsigned short* __restrict__ Eb, const float* __restrict__ V,
    const float* __restrict__ lbuf, const float* __restrict__ x,
    float* __restrict__ out)
{
  const int tid = threadIdx.x;
  const int nb = blockIdx.x * 128;
  const int mb = blockIdx.y * 128;
  const int b = blockIdx.z;
  const int lane = tid & 63, wv = tid >> 6;
  const int wm = (wv & 1) * 64, wn = (wv >> 1) * 64;
  const int l15 = lane & 15, l4 = lane >> 4;
  __shared__ unsigned short Ah[128 * 72];
  __shared__ unsigned short Bt[128 * 72];
  __shared__ float sl[128];
  if (tid < 128) sl[tid] = lbuf[b * 128 + tid];

  f32x4 acc[4][4];
  #pragma unroll
  for (int i = 0; i < 4; ++i)
    #pragma unroll
    for (int j = 0; j < 4; ++j) acc[i][j] = f32x4{0.f, 0.f, 0.f, 0.f};

  for (int kc = 0; kc < 128; kc += 64) {
    __syncthreads();
    #pragma unroll
    for (int j = 0; j < 8; ++j) {
      int flat = tid + 256 * j;
      int row = flat >> 4, s4 = (flat & 15) << 2;
      float4 v = *(const float4*)(V + ((size_t)(b * 512) + mb + row) * 128 + kc + s4);
      v.x *= sl[kc + s4]; v.y *= sl[kc + s4 + 1];
      v.z *= sl[kc + s4 + 2]; v.w *= sl[kc + s4 + 3];
      uint2 u; u.x = pack2(v.x, v.y); u.y = pack2(v.z, v.w);
      *(uint2*)&Ah[row * 72 + s4] = u;
    }
    #pragma unroll
    for (int j = 0; j < 4; ++j) {
      int flat = tid + 256 * j;
      int n = flat >> 3, s8 = (flat & 7) << 3;
      *(uint4*)&Bt[n * 72 + s8] =
          *(const uint4*)(Eb + ((size_t)(b * 4096) + nb + n) * 128 + kc + s8);
    }
    __syncthreads();
    #pragma unroll
    for (int kb = 0; kb < 64; kb += 32) {
      bf16x8 af[4], bfr[4];
      #pragma unroll
      for (int i = 0; i < 4; ++i)
        af[i] = *(const bf16x8*)&Ah[(wm + i * 16 + l15) * 72 + kb + l4 * 8];
      #pragma unroll
      for (int j = 0; j < 4; ++j)
        bfr[j] = *(const bf16x8*)&Bt[(wn + j * 16 + l15) * 72 + kb + l4 * 8];
      #pragma unroll
      for (int i = 0; i < 4; ++i)
        #pragma unroll
        for (int j = 0; j < 4; ++j)
          acc[i][j] = __builtin_amdgcn_mfma_f32_16x16x32_bf16(af[i], bfr[j], acc[i][j], 0, 0, 0);
    }
  }
  #pragma unroll
  for (int i = 0; i < 4; ++i)
    #pragma unroll
    for (int j = 0; j < 4; ++j)
      #pragma unroll
      for (int r = 0; r < 4; ++r) {
        int o = mb + wm + i * 16 + l4 * 4 + r;
        size_t idx = ((size_t)(b * 512) + o) * 4096 + nb + wn + j * 16 + l15;
        out[idx] = acc[i][j][r] + x[idx];
      }
}

// ---------------------------------------------------------------------------
extern "C" void kernel_launch(void* const* d_in, const int* in_sizes, int n_in,
                              void* d_out, int out_size, void* d_ws, size_t ws_size,
                              hipStream_t stream)
{
  (void)in_sizes; (void)n_in; (void)out_size; (void)ws_size;
  const float* x       = (const float*)d_in[0];
  const float* y       = (const float*)d_in[1];
  const float* w_phi   = (const float*)d_in[2];
  const float* w_theta = (const float*)d_in[3];
  const float* w_g     = (const float*)d_in[4];
  const float* w_mask  = (const float*)d_in[5];
  float* out = (float*)d_out;

  // Workspace: 130,039,808 B total (same as previous passing round).
  // Region A (67108864): yT, later overwritten by xT (after k1f).
  // Region B (54525952): Rbuf (18.9MB) -> scores (33.5MB, after k2f) | Eb | V.
  // Region C (~8.4MB): Pt, Pg, Kth, Ktl, mbuf, lbuf.
  char* ws = (char*)d_ws;
  unsigned short* yT = (unsigned short*)ws;
  unsigned short* xT = yT;                                    // alias: after k1f
  char* B0 = ws + 67108864;
  unsigned short* Rbuf = (unsigned short*)B0;                 // 18874368 B
  float* scores = (float*)B0;                                 // 33554432 B (after k2f)
  unsigned short* Eb = (unsigned short*)(B0 + 33554432);      // 16777216 B
  float* V = (float*)(B0 + 50331648);                         // 4194304 B
  char* C0 = B0 + 54525952;
  float* Pt = (float*)C0;                                     // 2097152
  float* Pg = (float*)(C0 + 2097152);                         // 2097152
  unsigned short* Kth = (unsigned short*)(C0 + 4194304);      // 2097152
  unsigned short* Ktl = (unsigned short*)(C0 + 6291456);      // 2097152
  float* mbuf = (float*)(C0 + 8388608);                       // 8192
  float* lbuf = (float*)(C0 + 8396800);                       // 8192

  p0_transpose<<<dim3(64, 8, 16), 256, 0, stream>>>(y, yT);
  k1f_conv_pool<<<dim3(128, 16), 256, 0, stream>>>(yT, w_theta, w_g, Rbuf);
  k2_pool_final<<<dim3(128, 16), 256, 0, stream>>>(Rbuf, Pt, Pg);
  k3_kmat<<<dim3(8, 16), 256, 0, stream>>>(Pt, w_phi, Kth, Ktl);
  k3_vmat<<<dim3(8, 16), 256, 0, stream>>>(Pg, w_mask, V);
  p0_transpose<<<dim3(64, 8, 16), 256, 0, stream>>>(x, xT);   // after k1f (alias)
  k4_scores<<<dim3(32, 16), 256, 0, stream>>>(xT, Kth, Ktl, scores); // after k2f (alias)
  k5_stats<<<dim3(128, 16), 256, 0, stream>>>(scores, mbuf, lbuf);
  k5e_expT<<<dim3(64, 16), 256, 0, stream>>>(scores, mbuf, Eb);
  k6_out<<<dim3(32, 4, 16), 256, 0, stream>>>(Eb, V, lbuf, x, out);
}

// Round 2
// 521.365 us; speedup vs baseline: 1.0605x; 1.0605x over previous
//
#include <hip/hip_runtime.h>

#define DI __device__ __forceinline__

typedef __attribute__((ext_vector_type(8))) __bf16 bf16x8;
typedef __attribute__((ext_vector_type(4))) float f32x4;

DI unsigned short f2bf(float x) {
  union { float f; unsigned u; } v; v.f = x;
  unsigned r = v.u + 0x7fffu + ((v.u >> 16) & 1u);
  return (unsigned short)(r >> 16);
}
DI float bf2f(unsigned short h) {
  union { unsigned u; float f; } v; v.u = ((unsigned)h) << 16;
  return v.f;
}
DI unsigned pack2(float a, float b) {
  return (unsigned)f2bf(a) | (((unsigned)f2bf(b)) << 16);
}

// Async global->LDS DMA, 16B per lane. LDS dest is wave-uniform base +
// lane*16; global src is per-lane. Drained by the vmcnt(0) the compiler
// emits before s_barrier (__syncthreads).
DI void gl_lds16(const void* g, void* l) {
  __builtin_amdgcn_global_load_lds(
      (const __attribute__((address_space(1))) void*)g,
      (__attribute__((address_space(3))) void*)l, 16, 0, 0);
}

// ---------------------------------------------------------------------------
// PW: one-time weight convert: [w_theta(256x512) ; w_g(256x512)] f32 -> bf16
// wTG [512][512]. Removes all per-block weight conversion from k1f.
// ---------------------------------------------------------------------------
__global__ __launch_bounds__(256) void pw_conv(
    const float* __restrict__ w_theta, const float* __restrict__ w_g,
    unsigned short* __restrict__ wTG)
{
  int e = (blockIdx.x * 256 + threadIdx.x) * 8;        // 0..262136, 8 elems
  const float* src = (e < 131072) ? (w_theta + e) : (w_g + (e - 131072));
  float4 a = *(const float4*)src;
  float4 c = *(const float4*)(src + 4);
  uint4 u;
  u.x = pack2(a.x, a.y); u.y = pack2(a.z, a.w);
  u.z = pack2(c.x, c.y); u.w = pack2(c.z, c.w);
  *(uint4*)(wTG + e) = u;
}

// ---------------------------------------------------------------------------
// P0: transpose-convert [b][512 c][4096 n] f32 -> [b][4096 n][512 c] bf16.
// 64x64 tiles via LDS (stride 65: conflict-free both sides).
// ---------------------------------------------------------------------------
__global__ __launch_bounds__(256) void p0_transpose(
    const float* __restrict__ src, unsigned short* __restrict__ dst)
{
  const int n0 = blockIdx.x * 64, c0 = blockIdx.y * 64, b = blockIdx.z;
  const int tid = threadIdx.x;
  __shared__ float T[64 * 65];
  #pragma unroll
  for (int p = 0; p < 4; ++p) {
    int r = p * 16 + (tid >> 4);
    int n4 = (tid & 15) << 2;
    *(float4*)&T[r * 65 + n4] =
        *(const float4*)(src + ((size_t)(b * 512 + c0 + r)) * 4096 + n0 + n4);
  }
  __syncthreads();
  int n = tid >> 2, cc = (tid & 3) * 16;
  unsigned u[8];
  #pragma unroll
  for (int j = 0; j < 16; j += 2)
    u[j >> 1] = pack2(T[(cc + j) * 65 + n], T[(cc + j + 1) * 65 + n]);
  unsigned short* d = dst + ((size_t)(b * 4096 + n0 + n)) * 512 + c0 + cc;
  *(uint4*)(d) = make_uint4(u[0], u[1], u[2], u[3]);
  *(uint4*)(d + 8) = make_uint4(u[4], u[5], u[6], u[7]);
}

// ---------------------------------------------------------------------------
// K1F: conv (theta|g) for a 128o x 128n tile via bf16 MFMA; BOTH operands now
// staged via global_load_lds (A from pre-converted wTG) -> zero VALU staging
// in the K-loop. Fused SPP w-bin pooling epilogue -> Rbuf[b][64 h][18][512].
// XCD-chunked tile swizzle keeps the 4 mb-blocks sharing a yT panel on one
// XCD's L2.
// ---------------------------------------------------------------------------
__constant__ int c_RS[18] = {0, 0,21,42, 0,10,21,32,42,53, 0,8,16,24,32,40,48,56};
__constant__ int c_RE[18] = {64, 22,43,64, 11,22,32,43,54,64, 8,16,24,32,40,48,56,64};

__global__ __launch_bounds__(256) void k1f_conv_pool(
    const unsigned short* __restrict__ yT, const unsigned short* __restrict__ wTG,
    unsigned short* __restrict__ Rbuf)
{
  const int tid = threadIdx.x;
  const int id = blockIdx.x;                    // 0..127 tiles within batch
  const int tile = (id & 7) * 16 + (id >> 3);   // XCD-chunked, bijective
  const int mb = (tile & 3) * 128;              // output-channel tile
  const int nbt = tile >> 2;                    // spatial tile index (0..31)
  const int nb = nbt * 128;
  const int b  = blockIdx.y;
  const int lane = tid & 63, wv = tid >> 6;
  const int wm = (wv & 1) * 64, wn = (wv >> 1) * 64;
  const int l15 = lane & 15, l4 = lane >> 4;

  __shared__ __align__(16) char smem[33280];    // staging 16KB | epi 33.3KB
  unsigned short* As = (unsigned short*)smem;            // [128][32] bf16
  unsigned short* Bs = (unsigned short*)(smem + 8192);   // [128][32] bf16
  float* P = (float*)smem;

  f32x4 acc[4][4];
  #pragma unroll
  for (int i = 0; i < 4; ++i)
    #pragma unroll
    for (int j = 0; j < 4; ++j) acc[i][j] = f32x4{0.f, 0.f, 0.f, 0.f};

  for (int kb = 0; kb < 512; kb += 32) {
    #pragma unroll
    for (int p = 0; p < 2; ++p) {
      int chunk = (wv * 2 + p) * 64 + lane;     // 16B chunk id, 0..511
      int row = chunk >> 2, c16 = chunk & 3;
      gl_lds16(wTG + ((size_t)(mb + row)) * 512 + kb + c16 * 8,
               As + (wv * 2 + p) * 512);
      gl_lds16(yT + ((size_t)(b * 4096 + nb + row)) * 512 + kb + c16 * 8,
               Bs + (wv * 2 + p) * 512);
    }
    __syncthreads();
    bf16x8 af[4], bfr[4];
    #pragma unroll
    for (int i = 0; i < 4; ++i)
      af[i] = *(const bf16x8*)&As[(wm + i * 16 + l15) * 32 + l4 * 8];
    #pragma unroll
    for (int j = 0; j < 4; ++j)
      bfr[j] = *(const bf16x8*)&Bs[(wn + j * 16 + l15) * 32 + l4 * 8];
    #pragma unroll
    for (int i = 0; i < 4; ++i)
      #pragma unroll
      for (int j = 0; j < 4; ++j)
        acc[i][j] = __builtin_amdgcn_mfma_f32_16x16x32_bf16(af[i], bfr[j], acc[i][j], 0, 0, 0);
    __syncthreads();
  }

  // Fused pooling epilogue: two passes (n-halves = image rows h, h+1).
  const int hloc = wv >> 1;
  #pragma unroll
  for (int pass = 0; pass < 2; ++pass) {
    __syncthreads();
    if (hloc == pass) {
      #pragma unroll
      for (int i = 0; i < 4; ++i)
        #pragma unroll
        for (int j = 0; j < 4; ++j)
          #pragma unroll
          for (int r = 0; r < 4; ++r)
            P[(wm + i * 16 + l4 * 4 + r) * 65 + j * 16 + l15] = acc[i][j][r];
    }
    __syncthreads();
    const int o = tid & 127;
    size_t rbase = (((size_t)(b * 64 + nbt * 2 + pass)) * 18) * 512 + mb + o;
    if (tid < 128) {
      float b0 = -3.4e38f, b1 = b0, b2 = b0, b3 = b0;
      #pragma unroll
      for (int w = 0; w < 64; ++w) {
        float v = P[o * 65 + w];
        b0 = fmaxf(b0, v);
        if (w < 22) b1 = fmaxf(b1, v);
        if (w >= 21 && w < 43) b2 = fmaxf(b2, v);
        if (w >= 42) b3 = fmaxf(b3, v);
      }
      Rbuf[rbase]           = f2bf(b0);
      Rbuf[rbase + 512]     = f2bf(b1);
      Rbuf[rbase + 2 * 512] = f2bf(b2);
      Rbuf[rbase + 3 * 512] = f2bf(b3);
    } else {
      float s6[6], s8[8];
      #pragma unroll
      for (int i = 0; i < 6; ++i) s6[i] = -3.4e38f;
      #pragma unroll
      for (int i = 0; i < 8; ++i) s8[i] = -3.4e38f;
      constexpr int R6S[6] = {0, 10, 21, 32, 42, 53};
      constexpr int R6E[6] = {11, 22, 32, 43, 54, 64};
      #pragma unroll
      for (int w = 0; w < 64; ++w) {
        float v = P[o * 65 + w];
        #pragma unroll
        for (int i = 0; i < 6; ++i)
          if (w >= R6S[i] && w < R6E[i]) s6[i] = fmaxf(s6[i], v);
        s8[w >> 3] = fmaxf(s8[w >> 3], v);
      }
      #pragma unroll
      for (int i = 0; i < 6; ++i) Rbuf[rbase + (size_t)(4 + i) * 512] = f2bf(s6[i]);
      #pragma unroll
      for (int i = 0; i < 8; ++i) Rbuf[rbase + (size_t)(10 + i) * 512] = f2bf(s8[i]);
    }
  }
}

// ---------------------------------------------------------------------------
// K2F: reduce Rbuf over h within each pyramid h-bin -> Pt/Pg [b][128 s][256].
// Rows s >= 110 zeroed (required by downstream K/score/exp path).
// ---------------------------------------------------------------------------
__global__ __launch_bounds__(256) void k2_pool_final(
    const unsigned short* __restrict__ Rbuf, float* __restrict__ Pt,
    float* __restrict__ Pg)
{
  const int s = blockIdx.x, b = blockIdx.y, tid = threadIdx.x;
  size_t obase = ((size_t)(b * 128) + s) * 256 + tid;
  if (s >= 110) { Pt[obase] = 0.f; Pg[obase] = 0.f; return; }
  int he, wb;
  if (s == 0)      { he = 0; wb = 0; }
  else if (s < 10) { int i = s - 1;  he = 1 + i / 3;  wb = 1 + i % 3; }
  else if (s < 46) { int i = s - 10; he = 4 + i / 6;  wb = 4 + i % 6; }
  else             { int i = s - 46; he = 10 + i / 8; wb = 10 + i % 8; }
  float m0 = -3.4e38f, m1 = -3.4e38f;
  int e = c_RE[he];
  for (int h = c_RS[he]; h < e; ++h) {
    const unsigned short* r = Rbuf + (((size_t)(b * 64 + h)) * 18 + wb) * 512;
    m0 = fmaxf(m0, bf2f(r[tid]));
    m1 = fmaxf(m1, bf2f(r[tid + 256]));
  }
  Pt[obase] = m0;
  Pg[obase] = m1;
}

// ---------------------------------------------------------------------------
// K3 (fused kmat+vmat, blockIdx.z selects):
//  z=0: Kt[b,s,c] = sum_ic w_phi[ic,c]*Pt[b,s,ic] -> hi/lo bf16 split
//  z=1: Vb[b,o,s] = bf16( sum_ic w_mask[o,ic]*Pg[b,s,ic] )
// One launch, 2x parallelism for these small latency-bound GEMMs.
// ---------------------------------------------------------------------------
__global__ __launch_bounds__(256) void k3_fused(
    const float* __restrict__ Pt, const float* __restrict__ Pg,
    const float* __restrict__ w_phi, const float* __restrict__ w_mask,
    unsigned short* __restrict__ Kth, unsigned short* __restrict__ Ktl,
    unsigned short* __restrict__ Vb)
{
  __shared__ __align__(16) char sm3[51200];
  const int tid = threadIdx.x;
  const int tx = tid & 15, ty = tid >> 4;
  const int b = blockIdx.y;
  if (blockIdx.z == 0) {
    const int ct = blockIdx.x;
    const int c0 = tx * 4, s0 = ty * 8;
    float* Ls = (float*)sm3;            // [128][64]
    float* Ws = Ls + 128 * 64;          // [64][68]
    float acc[8][4] = {};
    for (int kc = 0; kc < 256; kc += 64) {
      #pragma unroll
      for (int j = 0; j < 8; ++j) {
        int flat = tid + 256 * j;
        int row = flat >> 4, k4 = (flat & 15) << 2;
        *(float4*)&Ls[row * 64 + k4] =
            *(const float4*)(Pt + ((size_t)(b * 128) + row) * 256 + kc + k4);
      }
      #pragma unroll
      for (int j = 0; j < 4; ++j) {
        int flat = tid + 256 * j;
        int row = flat >> 4, c4 = (flat & 15) << 2;
        *(float4*)&Ws[row * 68 + c4] =
            *(const float4*)(w_phi + (size_t)(kc + row) * 512 + ct * 64 + c4);
      }
      __syncthreads();
      for (int k = 0; k < 64; k += 4) {
        float4 wv[4];
        #pragma unroll
        for (int kk = 0; kk < 4; ++kk) wv[kk] = *(const float4*)&Ws[(k + kk) * 68 + c0];
        #pragma unroll
        for (int i = 0; i < 8; ++i) {
          float4 a = *(const float4*)&Ls[(s0 + i) * 64 + k];
          const float* ap = (const float*)&a;
          #pragma unroll
          for (int kk = 0; kk < 4; ++kk) {
            const float* wp = (const float*)&wv[kk];
            acc[i][0] += ap[kk] * wp[0];
            acc[i][1] += ap[kk] * wp[1];
            acc[i][2] += ap[kk] * wp[2];
            acc[i][3] += ap[kk] * wp[3];
          }
        }
      }
      __syncthreads();
    }
    #pragma unroll
    for (int i = 0; i < 8; ++i) {
      unsigned short hi[4]; float lo[4];
      #pragma unroll
      for (int j = 0; j < 4; ++j) { hi[j] = f2bf(acc[i][j]); lo[j] = acc[i][j] - bf2f(hi[j]); }
      size_t base = ((size_t)(b * 128) + s0 + i) * 512 + ct * 64 + c0;
      uint2 uh; uh.x = (unsigned)hi[0] | ((unsigned)hi[1] << 16);
      uh.y = (unsigned)hi[2] | ((unsigned)hi[3] << 16);
      uint2 ul; ul.x = pack2(lo[0], lo[1]); ul.y = pack2(lo[2], lo[3]);
      *(uint2*)&Kth[base] = uh;
      *(uint2*)&Ktl[base] = ul;
    }
  } else {
    const int ot = blockIdx.x;
    const int o0 = ty * 4;
    float* Ws = (float*)sm3;            // [64][64]
    float* Ps = Ws + 64 * 64;           // [128][68]
    float acc[4][8] = {};
    for (int kc = 0; kc < 256; kc += 64) {
      #pragma unroll
      for (int j = 0; j < 4; ++j) {
        int flat = tid + 256 * j;
        int row = flat >> 4, k4 = (flat & 15) << 2;
        *(float4*)&Ws[row * 64 + k4] =
            *(const float4*)(w_mask + (size_t)(ot * 64 + row) * 256 + kc + k4);
      }
      #pragma unroll
      for (int j = 0; j < 8; ++j) {
        int flat = tid + 256 * j;
        int row = flat >> 4, k4 = (flat & 15) << 2;
        *(float4*)&Ps[row * 68 + k4] =
            *(const float4*)(Pg + ((size_t)(b * 128) + row) * 256 + kc + k4);
      }
      __syncthreads();
      for (int k = 0; k < 64; k += 4) {
        float4 wv[4];
        #pragma unroll
        for (int i = 0; i < 4; ++i) wv[i] = *(const float4*)&Ws[(o0 + i) * 64 + k];
        #pragma unroll
        for (int jj = 0; jj < 8; ++jj) {
          float4 pv = *(const float4*)&Ps[(tx + 16 * jj) * 68 + k];
          const float* pp = (const float*)&pv;
          #pragma unroll
          for (int i = 0; i < 4; ++i) {
            const float* wp = (const float*)&wv[i];
            #pragma unroll
            for (int kk = 0; kk < 4; ++kk) acc[i][jj] += wp[kk] * pp[kk];
          }
        }
      }
      __syncthreads();
    }
    #pragma unroll
    for (int i = 0; i < 4; ++i)
      #pragma unroll
      for (int jj = 0; jj < 8; ++jj)
        Vb[((size_t)(b * 512) + ot * 64 + o0 + i) * 128 + tx + 16 * jj] =
            f2bf(acc[i][jj]);
  }
}

// ---------------------------------------------------------------------------
// K4: scores[b,s,n] = sum_c Kt[b,s,c]*x[b,c,n]; Kt split hi/lo (2 MFMAs),
// all three operand stages via global_load_lds into linear [128][32] LDS.
// ---------------------------------------------------------------------------
__global__ __launch_bounds__(256) void k4_scores(
    const unsigned short* __restrict__ xT, const unsigned short* __restrict__ Kth,
    const unsigned short* __restrict__ Ktl, float* __restrict__ scores)
{
  const int tid = threadIdx.x;
  const int nb = blockIdx.x * 128;
  const int b = blockIdx.y;
  const int lane = tid & 63, wv = tid >> 6;
  const int wm = (wv & 1) * 64, wn = (wv >> 1) * 64;
  const int l15 = lane & 15, l4 = lane >> 4;
  __shared__ __align__(16) unsigned short Ah[128 * 32];
  __shared__ __align__(16) unsigned short Al[128 * 32];
  __shared__ __align__(16) unsigned short Bs[128 * 32];
  f32x4 acc[4][4];
  #pragma unroll
  for (int i = 0; i < 4; ++i)
    #pragma unroll
    for (int j = 0; j < 4; ++j) acc[i][j] = f32x4{0.f, 0.f, 0.f, 0.f};

  for (int kb = 0; kb < 512; kb += 32) {
    #pragma unroll
    for (int p = 0; p < 2; ++p) {
      int chunk = (wv * 2 + p) * 64 + lane;
      int row = chunk >> 2, c16 = chunk & 3;
      size_t g = ((size_t)(b * 128) + row) * 512 + kb + c16 * 8;
      gl_lds16(Kth + g, Ah + (wv * 2 + p) * 512);
      gl_lds16(Ktl + g, Al + (wv * 2 + p) * 512);
      gl_lds16(xT + ((size_t)(b * 4096 + nb + row)) * 512 + kb + c16 * 8,
               Bs + (wv * 2 + p) * 512);
    }
    __syncthreads();
    bf16x8 ah[4], al[4], bfr[4];
    #pragma unroll
    for (int i = 0; i < 4; ++i) {
      ah[i] = *(const bf16x8*)&Ah[(wm + i * 16 + l15) * 32 + l4 * 8];
      al[i] = *(const bf16x8*)&Al[(wm + i * 16 + l15) * 32 + l4 * 8];
    }
    #pragma unroll
    for (int j = 0; j < 4; ++j)
      bfr[j] = *(const bf16x8*)&Bs[(wn + j * 16 + l15) * 32 + l4 * 8];
    #pragma unroll
    for (int i = 0; i < 4; ++i)
      #pragma unroll
      for (int j = 0; j < 4; ++j) {
        acc[i][j] = __builtin_amdgcn_mfma_f32_16x16x32_bf16(ah[i], bfr[j], acc[i][j], 0, 0, 0);
        acc[i][j] = __builtin_amdgcn_mfma_f32_16x16x32_bf16(al[i], bfr[j], acc[i][j], 0, 0, 0);
      }
    __syncthreads();
  }
  #pragma unroll
  for (int i = 0; i < 4; ++i)
    #pragma unroll
    for (int j = 0; j < 4; ++j)
      #pragma unroll
      for (int r = 0; r < 4; ++r)
        scores[((size_t)(b * 128) + wm + i * 16 + l4 * 4 + r) * 4096 + nb + wn + j * 16 + l15] =
            acc[i][j][r];
}

// ---------------------------------------------------------------------------
// K5: per-(b,s) softmax stats over N=4096: m = max, linv = 1/sum(exp(v-m))
// ---------------------------------------------------------------------------
__global__ __launch_bounds__(256) void k5_stats(
    const float* __restrict__ scores, float* __restrict__ mbuf,
    float* __restrict__ lbuf)
{
  const int s = blockIdx.x, b = blockIdx.y, tid = threadIdx.x;
  if (s >= 110) {
    if (tid == 0) { mbuf[b * 128 + s] = 0.f; lbuf[b * 128 + s] = 0.f; }
    return;
  }
  const float* row = scores + ((size_t)(b * 128) + s) * 4096;
  float4 v[4];
  float m = -3.4e38f;
  #pragma unroll
  for (int j = 0; j < 4; ++j) {
    v[j] = *(const float4*)(row + (tid + 256 * j) * 4);
    m = fmaxf(m, fmaxf(fmaxf(v[j].x, v[j].y), fmaxf(v[j].z, v[j].w)));
  }
  #pragma unroll
  for (int off = 32; off > 0; off >>= 1) m = fmaxf(m, __shfl_down(m, off));
  __shared__ float red[8];
  if ((tid & 63) == 0) red[tid >> 6] = m;
  __syncthreads();
  float mm = fmaxf(fmaxf(red[0], red[1]), fmaxf(red[2], red[3]));
  float sum = 0.f;
  #pragma unroll
  for (int j = 0; j < 4; ++j)
    sum += __expf(v[j].x - mm) + __expf(v[j].y - mm) +
           __expf(v[j].z - mm) + __expf(v[j].w - mm);
  #pragma unroll
  for (int off = 32; off > 0; off >>= 1) sum += __shfl_down(sum, off);
  if ((tid & 63) == 0) red[4 + (tid >> 6)] = sum;
  __syncthreads();
  if (tid == 0) {
    float S = red[4] + red[5] + red[6] + red[7];
    mbuf[b * 128 + s] = mm;
    lbuf[b * 128 + s] = 1.f / S;
  }
}

// ---------------------------------------------------------------------------
// K5E: Eb[b,n,s] = bf16( exp(scores[b,s,n]-m[b,s]) * linv[b,s] )
// (linv folded here so k6's A operand is a straight bf16 copy)
// ---------------------------------------------------------------------------
__global__ __launch_bounds__(256) void k5e_expT(
    const float* __restrict__ scores, const float* __restrict__ mbuf,
    const float* __restrict__ lbuf, unsigned short* __restrict__ Eb)
{
  const int nt = blockIdx.x, b = blockIdx.y, tid = threadIdx.x;
  __shared__ float L[128 * 68];
  __shared__ float sm[128], sl[128];
  if (tid < 128) { sm[tid] = mbuf[b * 128 + tid]; sl[tid] = lbuf[b * 128 + tid]; }
  #pragma unroll
  for (int j = 0; j < 8; ++j) {
    int flat = tid + 256 * j;
    int s = flat >> 4, n4 = (flat & 15) << 2;
    *(float4*)&L[s * 68 + n4] =
        *(const float4*)(scores + ((size_t)(b * 128) + s) * 4096 + nt * 64 + n4);
  }
  __syncthreads();
  int n = tid >> 2, sq = (tid & 3) * 32;
  unsigned ub[16];
  #pragma unroll
  for (int k = 0; k < 32; k += 2) {
    float e0 = __expf(L[(sq + k) * 68 + n] - sm[sq + k]) * sl[sq + k];
    float e1 = __expf(L[(sq + k + 1) * 68 + n] - sm[sq + k + 1]) * sl[sq + k + 1];
    ub[k >> 1] = pack2(e0, e1);
  }
  uint4* dst = (uint4*)(Eb + ((size_t)(b * 4096) + nt * 64 + n) * 128 + sq);
  #pragma unroll
  for (int j = 0; j < 4; ++j)
    dst[j] = make_uint4(ub[4 * j], ub[4 * j + 1], ub[4 * j + 2], ub[4 * j + 3]);
}

// ---------------------------------------------------------------------------
// K6: out[b,o,n] = sum_s Vb[b,o,s] * Eb[b,n,s] + x[b,o,n]
// Fully DMA-staged: 4 linear [128][32] slabs per kc-half (verified
// conflict-free wave bank spread). No VALU staging in the loop.
// ---------------------------------------------------------------------------
__global__ __launch_bounds__(256) void k6_out(
    const unsigned short* __restrict__ Eb, const unsigned short* __restrict__ Vb,
    const float* __restrict__ x, float* __restrict__ out)
{
  const int tid = threadIdx.x;
  const int nb = blockIdx.x * 128;
  const int mb = blockIdx.y * 128;
  const int b = blockIdx.z;
  const int lane = tid & 63, wv = tid >> 6;
  const int wm = (wv & 1) * 64, wn = (wv >> 1) * 64;
  const int l15 = lane & 15, l4 = lane >> 4;
  __shared__ __align__(16) unsigned short A0[128 * 32];
  __shared__ __align__(16) unsigned short A1[128 * 32];
  __shared__ __align__(16) unsigned short B0[128 * 32];
  __shared__ __align__(16) unsigned short B1[128 * 32];

  f32x4 acc[4][4];
  #pragma unroll
  for (int i = 0; i < 4; ++i)
    #pragma unroll
    for (int j = 0; j < 4; ++j) acc[i][j] = f32x4{0.f, 0.f, 0.f, 0.f};

  for (int kc = 0; kc < 128; kc += 64) {
    #pragma unroll
    for (int p = 0; p < 2; ++p) {
      int chunk = (wv * 2 + p) * 64 + lane;
      int row = chunk >> 2, c16 = chunk & 3;
      size_t ga = ((size_t)(b * 512) + mb + row) * 128 + kc + c16 * 8;
      gl_lds16(Vb + ga,      A0 + (wv * 2 + p) * 512);
      gl_lds16(Vb + ga + 32, A1 + (wv * 2 + p) * 512);
      size_t gb = ((size_t)(b * 4096) + nb + row) * 128 + kc + c16 * 8;
      gl_lds16(Eb + gb,      B0 + (wv * 2 + p) * 512);
      gl_lds16(Eb + gb + 32, B1 + (wv * 2 + p) * 512);
    }
    __syncthreads();
    #pragma unroll
    for (int h = 0; h < 2; ++h) {
      const unsigned short* Ak = h ? A1 : A0;
      const unsigned short* Bk = h ? B1 : B0;
      bf16x8 af[4], bfr[4];
      #pragma unroll
      for (int i = 0; i < 4; ++i)
        af[i] = *(const bf16x8*)&Ak[(wm + i * 16 + l15) * 32 + l4 * 8];
      #pragma unroll
      for (int j = 0; j < 4; ++j)
        bfr[j] = *(const bf16x8*)&Bk[(wn + j * 16 + l15) * 32 + l4 * 8];
      #pragma unroll
      for (int i = 0; i < 4; ++i)
        #pragma unroll
        for (int j = 0; j < 4; ++j)
          acc[i][j] = __builtin_amdgcn_mfma_f32_16x16x32_bf16(af[i], bfr[j], acc[i][j], 0, 0, 0);
    }
    __syncthreads();
  }
  #pragma unroll
  for (int i = 0; i < 4; ++i)
    #pragma unroll
    for (int j = 0; j < 4; ++j)
      #pragma unroll
      for (int r = 0; r < 4; ++r) {
        int o = mb + wm + i * 16 + l4 * 4 + r;
        size_t idx = ((size_t)(b * 512) + o) * 4096 + nb + wn + j * 16 + l15;
        out[idx] = acc[i][j][r] + x[idx];
      }
}

// ---------------------------------------------------------------------------
extern "C" void kernel_launch(void* const* d_in, const int* in_sizes, int n_in,
                              void* d_out, int out_size, void* d_ws, size_t ws_size,
                              hipStream_t stream)
{
  (void)in_sizes; (void)n_in; (void)out_size; (void)ws_size;
  const float* x       = (const float*)d_in[0];
  const float* y       = (const float*)d_in[1];
  const float* w_phi   = (const float*)d_in[2];
  const float* w_theta = (const float*)d_in[3];
  const float* w_g     = (const float*)d_in[4];
  const float* w_mask  = (const float*)d_in[5];
  float* out = (float*)d_out;

  // Workspace: 130,039,808 B total.
  // Region A (67108864): yT, later overwritten by xT (after k1f).
  // Region B (54525952): Rbuf (18.9MB) -> scores (33.5MB) | Eb (16.8MB) |
  //   old-V slot (4MB) time-shared: wTG (512KB, pw->k1f) then Vb (2MB, k3->k6).
  // Region C (8404992): Pt, Pg, Kth, Ktl, mbuf, lbuf (exactly full).
  char* ws = (char*)d_ws;
  unsigned short* yT = (unsigned short*)ws;
  unsigned short* xT = yT;                                    // alias: after k1f
  char* B0 = ws + 67108864;
  unsigned short* Rbuf = (unsigned short*)B0;                 // 18874368 B
  float* scores = (float*)B0;                                 // 33554432 B (after k2)
  unsigned short* Eb = (unsigned short*)(B0 + 33554432);      // 16777216 B
  unsigned short* wTG = (unsigned short*)(B0 + 50331648);     // 524288 B (pw->k1f)
  unsigned short* Vb  = (unsigned short*)(B0 + 50331648);     // 2097152 B (k3->k6)
  char* C0 = B0 + 54525952;
  float* Pt = (float*)C0;                                     // 2097152
  float* Pg = (float*)(C0 + 2097152);                         // 2097152
  unsigned short* Kth = (unsigned short*)(C0 + 4194304);      // 2097152
  unsigned short* Ktl = (unsigned short*)(C0 + 6291456);      // 2097152
  float* mbuf = (float*)(C0 + 8388608);                       // 8192
  float* lbuf = (float*)(C0 + 8396800);                       // 8192

  pw_conv<<<dim3(128), 256, 0, stream>>>(w_theta, w_g, wTG);
  p0_transpose<<<dim3(64, 8, 16), 256, 0, stream>>>(y, yT);
  k1f_conv_pool<<<dim3(128, 16), 256, 0, stream>>>(yT, wTG, Rbuf);
  k2_pool_final<<<dim3(128, 16), 256, 0, stream>>>(Rbuf, Pt, Pg);
  k3_fused<<<dim3(8, 16, 2), 256, 0, stream>>>(Pt, Pg, w_phi, w_mask, Kth, Ktl, Vb);
  p0_transpose<<<dim3(64, 8, 16), 256, 0, stream>>>(x, xT);   // after k1f (alias)
  k4_scores<<<dim3(32, 16), 256, 0, stream>>>(xT, Kth, Ktl, scores); // after k2 (alias)
  k5_stats<<<dim3(128, 16), 256, 0, stream>>>(scores, mbuf, lbuf);
  k5e_expT<<<dim3(64, 16), 256, 0, stream>>>(scores, mbuf, lbuf, Eb);
  k6_out<<<dim3(32, 4, 16), 256, 0, stream>>>(Eb, Vb, x, out);
}

// Round 3
// 501.253 us; speedup vs baseline: 1.1030x; 1.0401x over previous
//
#include <hip/hip_runtime.h>

#define DI __device__ __forceinline__

typedef __attribute__((ext_vector_type(8))) __bf16 bf16x8;
typedef __attribute__((ext_vector_type(4))) float f32x4;

DI unsigned short f2bf(float x) {
  union { float f; unsigned u; } v; v.f = x;
  unsigned r = v.u + 0x7fffu + ((v.u >> 16) & 1u);
  return (unsigned short)(r >> 16);
}
DI float bf2f(unsigned short h) {
  union { unsigned u; float f; } v; v.u = ((unsigned)h) << 16;
  return v.f;
}
DI unsigned pack2(float a, float b) {
  return (unsigned)f2bf(a) | (((unsigned)f2bf(b)) << 16);
}

// Async global->LDS DMA, 16B per lane. LDS dest is wave-uniform base +
// lane*16; global src is per-lane. Drained by the vmcnt(0) the compiler
// emits before s_barrier (__syncthreads).
DI void gl_lds16(const void* g, void* l) {
  __builtin_amdgcn_global_load_lds(
      (const __attribute__((address_space(1))) void*)g,
      (__attribute__((address_space(3))) void*)l, 16, 0, 0);
}

// ---------------------------------------------------------------------------
// P0W: transpose-convert [b][512 c][4096 n] f32 -> [b][4096 n][512 c] bf16
// (z<16), plus one-time weight convert w_theta|w_g -> bf16 wTG on the z==16
// slice (only launched with gridDim.z=17 for the y pass).
// ---------------------------------------------------------------------------
__global__ __launch_bounds__(256) void p0w_transpose(
    const float* __restrict__ src, unsigned short* __restrict__ dst,
    const float* __restrict__ w_theta, const float* __restrict__ w_g,
    unsigned short* __restrict__ wTG)
{
  if (blockIdx.z == 16) {                       // pw slice (y launch only)
    if (blockIdx.y < 2) {
      int e = ((blockIdx.y * 64 + blockIdx.x) * 256 + threadIdx.x) * 8;
      const float* s = (e < 131072) ? (w_theta + e) : (w_g + (e - 131072));
      float4 a = *(const float4*)s;
      float4 c = *(const float4*)(s + 4);
      uint4 u;
      u.x = pack2(a.x, a.y); u.y = pack2(a.z, a.w);
      u.z = pack2(c.x, c.y); u.w = pack2(c.z, c.w);
      *(uint4*)(wTG + e) = u;
    }
    return;
  }
  const int n0 = blockIdx.x * 64, c0 = blockIdx.y * 64, b = blockIdx.z;
  const int tid = threadIdx.x;
  __shared__ float T[64 * 65];
  #pragma unroll
  for (int p = 0; p < 4; ++p) {
    int r = p * 16 + (tid >> 4);
    int n4 = (tid & 15) << 2;
    *(float4*)&T[r * 65 + n4] =
        *(const float4*)(src + ((size_t)(b * 512 + c0 + r)) * 4096 + n0 + n4);
  }
  __syncthreads();
  int n = tid >> 2, cc = (tid & 3) * 16;
  unsigned u[8];
  #pragma unroll
  for (int j = 0; j < 16; j += 2)
    u[j >> 1] = pack2(T[(cc + j) * 65 + n], T[(cc + j + 1) * 65 + n]);
  unsigned short* d = dst + ((size_t)(b * 4096 + n0 + n)) * 512 + c0 + cc;
  *(uint4*)(d) = make_uint4(u[0], u[1], u[2], u[3]);
  *(uint4*)(d + 8) = make_uint4(u[4], u[5], u[6], u[7]);
}

// ---------------------------------------------------------------------------
// K1F: conv (theta|g) 128o x 128n tile via bf16 MFMA, both operands DMA'd
// (global_load_lds) with 2-phase double-buffer: STAGE(t+1) overlaps MFMA(t),
// ONE barrier per K-step. Fused SPP w-bin pooling epilogue (LDS union).
// ---------------------------------------------------------------------------
__constant__ int c_RS[18] = {0, 0,21,42, 0,10,21,32,42,53, 0,8,16,24,32,40,48,56};
__constant__ int c_RE[18] = {64, 22,43,64, 11,22,32,43,54,64, 8,16,24,32,40,48,56,64};

__global__ __launch_bounds__(256) void k1f_conv_pool(
    const unsigned short* __restrict__ yT, const unsigned short* __restrict__ wTG,
    unsigned short* __restrict__ Rbuf)
{
  const int tid = threadIdx.x;
  const int id = blockIdx.x;
  const int tile = (id & 7) * 16 + (id >> 3);   // XCD-chunked, bijective
  const int mb = (tile & 3) * 128;
  const int nbt = tile >> 2;
  const int nb = nbt * 128;
  const int b  = blockIdx.y;
  const int lane = tid & 63, wv = tid >> 6;
  const int wm = (wv & 1) * 64, wn = (wv >> 1) * 64;
  const int l15 = lane & 15, l4 = lane >> 4;

  __shared__ __align__(16) char smem[33280];    // dbuf staging 32KB | epi 33.3KB
  float* P = (float*)smem;

  f32x4 acc[4][4];
  #pragma unroll
  for (int i = 0; i < 4; ++i)
    #pragma unroll
    for (int j = 0; j < 4; ++j) acc[i][j] = f32x4{0.f, 0.f, 0.f, 0.f};

  auto stage = [&](int buf, int kb) {
    unsigned short* As = (unsigned short*)(smem + buf * 16384);
    unsigned short* Bs = As + 4096;
    #pragma unroll
    for (int p = 0; p < 2; ++p) {
      int chunk = (wv * 2 + p) * 64 + lane;     // 16B chunk id, 0..511
      int row = chunk >> 2, c16 = chunk & 3;
      gl_lds16(wTG + ((size_t)(mb + row)) * 512 + kb + c16 * 8,
               As + (wv * 2 + p) * 512);
      gl_lds16(yT + ((size_t)(b * 4096 + nb + row)) * 512 + kb + c16 * 8,
               Bs + (wv * 2 + p) * 512);
    }
  };

  stage(0, 0);
  __syncthreads();
  int cur = 0;
  for (int t = 0; t < 16; ++t) {
    if (t < 15) stage(cur ^ 1, (t + 1) * 32);
    const unsigned short* As = (const unsigned short*)(smem + cur * 16384);
    const unsigned short* Bs = As + 4096;
    bf16x8 af[4], bfr[4];
    #pragma unroll
    for (int i = 0; i < 4; ++i)
      af[i] = *(const bf16x8*)&As[(wm + i * 16 + l15) * 32 + l4 * 8];
    #pragma unroll
    for (int j = 0; j < 4; ++j)
      bfr[j] = *(const bf16x8*)&Bs[(wn + j * 16 + l15) * 32 + l4 * 8];
    #pragma unroll
    for (int i = 0; i < 4; ++i)
      #pragma unroll
      for (int j = 0; j < 4; ++j)
        acc[i][j] = __builtin_amdgcn_mfma_f32_16x16x32_bf16(af[i], bfr[j], acc[i][j], 0, 0, 0);
    __syncthreads();
    cur ^= 1;
  }

  // Fused pooling epilogue: two passes (n-halves = image rows h, h+1).
  const int hloc = wv >> 1;
  #pragma unroll
  for (int pass = 0; pass < 2; ++pass) {
    __syncthreads();
    if (hloc == pass) {
      #pragma unroll
      for (int i = 0; i < 4; ++i)
        #pragma unroll
        for (int j = 0; j < 4; ++j)
          #pragma unroll
          for (int r = 0; r < 4; ++r)
            P[(wm + i * 16 + l4 * 4 + r) * 65 + j * 16 + l15] = acc[i][j][r];
    }
    __syncthreads();
    const int o = tid & 127;
    size_t rbase = (((size_t)(b * 64 + nbt * 2 + pass)) * 18) * 512 + mb + o;
    if (tid < 128) {
      float b0 = -3.4e38f, b1 = b0, b2 = b0, b3 = b0;
      #pragma unroll
      for (int w = 0; w < 64; ++w) {
        float v = P[o * 65 + w];
        b0 = fmaxf(b0, v);
        if (w < 22) b1 = fmaxf(b1, v);
        if (w >= 21 && w < 43) b2 = fmaxf(b2, v);
        if (w >= 42) b3 = fmaxf(b3, v);
      }
      Rbuf[rbase]           = f2bf(b0);
      Rbuf[rbase + 512]     = f2bf(b1);
      Rbuf[rbase + 2 * 512] = f2bf(b2);
      Rbuf[rbase + 3 * 512] = f2bf(b3);
    } else {
      float s6[6], s8[8];
      #pragma unroll
      for (int i = 0; i < 6; ++i) s6[i] = -3.4e38f;
      #pragma unroll
      for (int i = 0; i < 8; ++i) s8[i] = -3.4e38f;
      constexpr int R6S[6] = {0, 10, 21, 32, 42, 53};
      constexpr int R6E[6] = {11, 22, 32, 43, 54, 64};
      #pragma unroll
      for (int w = 0; w < 64; ++w) {
        float v = P[o * 65 + w];
        #pragma unroll
        for (int i = 0; i < 6; ++i)
          if (w >= R6S[i] && w < R6E[i]) s6[i] = fmaxf(s6[i], v);
        s8[w >> 3] = fmaxf(s8[w >> 3], v);
      }
      #pragma unroll
      for (int i = 0; i < 6; ++i) Rbuf[rbase + (size_t)(4 + i) * 512] = f2bf(s6[i]);
      #pragma unroll
      for (int i = 0; i < 8; ++i) Rbuf[rbase + (size_t)(10 + i) * 512] = f2bf(s8[i]);
    }
  }
}

// ---------------------------------------------------------------------------
// K2F: reduce Rbuf over h within each pyramid h-bin -> Pt/Pg [b][128 s][256].
// ---------------------------------------------------------------------------
__global__ __launch_bounds__(256) void k2_pool_final(
    const unsigned short* __restrict__ Rbuf, float* __restrict__ Pt,
    float* __restrict__ Pg)
{
  const int s = blockIdx.x, b = blockIdx.y, tid = threadIdx.x;
  size_t obase = ((size_t)(b * 128) + s) * 256 + tid;
  if (s >= 110) { Pt[obase] = 0.f; Pg[obase] = 0.f; return; }
  int he, wb;
  if (s == 0)      { he = 0; wb = 0; }
  else if (s < 10) { int i = s - 1;  he = 1 + i / 3;  wb = 1 + i % 3; }
  else if (s < 46) { int i = s - 10; he = 4 + i / 6;  wb = 4 + i % 6; }
  else             { int i = s - 46; he = 10 + i / 8; wb = 10 + i % 8; }
  float m0 = -3.4e38f, m1 = -3.4e38f;
  int e = c_RE[he];
  for (int h = c_RS[he]; h < e; ++h) {
    const unsigned short* r = Rbuf + (((size_t)(b * 64 + h)) * 18 + wb) * 512;
    m0 = fmaxf(m0, bf2f(r[tid]));
    m1 = fmaxf(m1, bf2f(r[tid + 256]));
  }
  Pt[obase] = m0;
  Pg[obase] = m1;
}

// ---------------------------------------------------------------------------
// K3 (fused kmat+vmat, blockIdx.z selects):
//  z=0: Kt[b,s,c] = sum_ic w_phi[ic,c]*Pt[b,s,ic] -> hi/lo bf16 split
//  z=1: Vb[b,o,s] = bf16( sum_ic w_mask[o,ic]*Pg[b,s,ic] )
// ---------------------------------------------------------------------------
__global__ __launch_bounds__(256) void k3_fused(
    const float* __restrict__ Pt, const float* __restrict__ Pg,
    const float* __restrict__ w_phi, const float* __restrict__ w_mask,
    unsigned short* __restrict__ Kth, unsigned short* __restrict__ Ktl,
    unsigned short* __restrict__ Vb)
{
  __shared__ __align__(16) char sm3[51200];
  const int tid = threadIdx.x;
  const int tx = tid & 15, ty = tid >> 4;
  const int b = blockIdx.y;
  if (blockIdx.z == 0) {
    const int ct = blockIdx.x;
    const int c0 = tx * 4, s0 = ty * 8;
    float* Ls = (float*)sm3;            // [128][64]
    float* Ws = Ls + 128 * 64;          // [64][68]
    float acc[8][4] = {};
    for (int kc = 0; kc < 256; kc += 64) {
      #pragma unroll
      for (int j = 0; j < 8; ++j) {
        int flat = tid + 256 * j;
        int row = flat >> 4, k4 = (flat & 15) << 2;
        *(float4*)&Ls[row * 64 + k4] =
            *(const float4*)(Pt + ((size_t)(b * 128) + row) * 256 + kc + k4);
      }
      #pragma unroll
      for (int j = 0; j < 4; ++j) {
        int flat = tid + 256 * j;
        int row = flat >> 4, c4 = (flat & 15) << 2;
        *(float4*)&Ws[row * 68 + c4] =
            *(const float4*)(w_phi + (size_t)(kc + row) * 512 + ct * 64 + c4);
      }
      __syncthreads();
      for (int k = 0; k < 64; k += 4) {
        float4 wv[4];
        #pragma unroll
        for (int kk = 0; kk < 4; ++kk) wv[kk] = *(const float4*)&Ws[(k + kk) * 68 + c0];
        #pragma unroll
        for (int i = 0; i < 8; ++i) {
          float4 a = *(const float4*)&Ls[(s0 + i) * 64 + k];
          const float* ap = (const float*)&a;
          #pragma unroll
          for (int kk = 0; kk < 4; ++kk) {
            const float* wp = (const float*)&wv[kk];
            acc[i][0] += ap[kk] * wp[0];
            acc[i][1] += ap[kk] * wp[1];
            acc[i][2] += ap[kk] * wp[2];
            acc[i][3] += ap[kk] * wp[3];
          }
        }
      }
      __syncthreads();
    }
    #pragma unroll
    for (int i = 0; i < 8; ++i) {
      unsigned short hi[4]; float lo[4];
      #pragma unroll
      for (int j = 0; j < 4; ++j) { hi[j] = f2bf(acc[i][j]); lo[j] = acc[i][j] - bf2f(hi[j]); }
      size_t base = ((size_t)(b * 128) + s0 + i) * 512 + ct * 64 + c0;
      uint2 uh; uh.x = (unsigned)hi[0] | ((unsigned)hi[1] << 16);
      uh.y = (unsigned)hi[2] | ((unsigned)hi[3] << 16);
      uint2 ul; ul.x = pack2(lo[0], lo[1]); ul.y = pack2(lo[2], lo[3]);
      *(uint2*)&Kth[base] = uh;
      *(uint2*)&Ktl[base] = ul;
    }
  } else {
    const int ot = blockIdx.x;
    const int o0 = ty * 4;
    float* Ws = (float*)sm3;            // [64][64]
    float* Ps = Ws + 64 * 64;           // [128][68]
    float acc[4][8] = {};
    for (int kc = 0; kc < 256; kc += 64) {
      #pragma unroll
      for (int j = 0; j < 4; ++j) {
        int flat = tid + 256 * j;
        int row = flat >> 4, k4 = (flat & 15) << 2;
        *(float4*)&Ws[row * 64 + k4] =
            *(const float4*)(w_mask + (size_t)(ot * 64 + row) * 256 + kc + k4);
      }
      #pragma unroll
      for (int j = 0; j < 8; ++j) {
        int flat = tid + 256 * j;
        int row = flat >> 4, k4 = (flat & 15) << 2;
        *(float4*)&Ps[row * 68 + k4] =
            *(const float4*)(Pg + ((size_t)(b * 128) + row) * 256 + kc + k4);
      }
      __syncthreads();
      for (int k = 0; k < 64; k += 4) {
        float4 wv[4];
        #pragma unroll
        for (int i = 0; i < 4; ++i) wv[i] = *(const float4*)&Ws[(o0 + i) * 64 + k];
        #pragma unroll
        for (int jj = 0; jj < 8; ++jj) {
          float4 pv = *(const float4*)&Ps[(tx + 16 * jj) * 68 + k];
          const float* pp = (const float*)&pv;
          #pragma unroll
          for (int i = 0; i < 4; ++i) {
            const float* wp = (const float*)&wv[i];
            #pragma unroll
            for (int kk = 0; kk < 4; ++kk) acc[i][jj] += wp[kk] * pp[kk];
          }
        }
      }
      __syncthreads();
    }
    #pragma unroll
    for (int i = 0; i < 4; ++i)
      #pragma unroll
      for (int jj = 0; jj < 8; ++jj)
        Vb[((size_t)(b * 512) + ot * 64 + o0 + i) * 128 + tx + 16 * jj] =
            f2bf(acc[i][jj]);
  }
}

// ---------------------------------------------------------------------------
// K4: scores[b,s,n] = sum_c Kt[b,s,c]*x[b,c,n]; hi/lo split (2 MFMAs). All
// operands DMA'd, 2-phase double-buffer (one barrier/K-step). Epilogue also
// emits per-(s, n-tile) softmax partials (max, sum-exp) so K5 is not needed.
// ---------------------------------------------------------------------------
__global__ __launch_bounds__(256) void k4_scores(
    const unsigned short* __restrict__ xT, const unsigned short* __restrict__ Kth,
    const unsigned short* __restrict__ Ktl, float* __restrict__ scores,
    float* __restrict__ pmax_g, float* __restrict__ psum_g)
{
  const int tid = threadIdx.x;
  const int ntile = blockIdx.x;
  const int nb = ntile * 128;
  const int b = blockIdx.y;
  const int lane = tid & 63, wv = tid >> 6;
  const int wm = (wv & 1) * 64, wn = (wv >> 1) * 64;
  const int l15 = lane & 15, l4 = lane >> 4;
  __shared__ __align__(16) char smem4[49152];   // 2 x (Ah|Al|Bs) 8KB slabs
  __shared__ float SmP[256], SsP[256];          // [s][n-half] partials
  f32x4 acc[4][4];
  #pragma unroll
  for (int i = 0; i < 4; ++i)
    #pragma unroll
    for (int j = 0; j < 4; ++j) acc[i][j] = f32x4{0.f, 0.f, 0.f, 0.f};

  auto stage = [&](int buf, int kb) {
    unsigned short* Ah = (unsigned short*)(smem4 + buf * 24576);
    unsigned short* Al = Ah + 4096;
    unsigned short* Bs = Al + 4096;
    #pragma unroll
    for (int p = 0; p < 2; ++p) {
      int chunk = (wv * 2 + p) * 64 + lane;
      int row = chunk >> 2, c16 = chunk & 3;
      size_t g = ((size_t)(b * 128) + row) * 512 + kb + c16 * 8;
      gl_lds16(Kth + g, Ah + (wv * 2 + p) * 512);
      gl_lds16(Ktl + g, Al + (wv * 2 + p) * 512);
      gl_lds16(xT + ((size_t)(b * 4096 + nb + row)) * 512 + kb + c16 * 8,
               Bs + (wv * 2 + p) * 512);
    }
  };

  stage(0, 0);
  __syncthreads();
  int cur = 0;
  for (int t = 0; t < 16; ++t) {
    if (t < 15) stage(cur ^ 1, (t + 1) * 32);
    const unsigned short* Ah = (const unsigned short*)(smem4 + cur * 24576);
    const unsigned short* Al = Ah + 4096;
    const unsigned short* Bs = Al + 4096;
    bf16x8 ah[4], al[4], bfr[4];
    #pragma unroll
    for (int i = 0; i < 4; ++i) {
      ah[i] = *(const bf16x8*)&Ah[(wm + i * 16 + l15) * 32 + l4 * 8];
      al[i] = *(const bf16x8*)&Al[(wm + i * 16 + l15) * 32 + l4 * 8];
    }
    #pragma unroll
    for (int j = 0; j < 4; ++j)
      bfr[j] = *(const bf16x8*)&Bs[(wn + j * 16 + l15) * 32 + l4 * 8];
    #pragma unroll
    for (int i = 0; i < 4; ++i)
      #pragma unroll
      for (int j = 0; j < 4; ++j) {
        acc[i][j] = __builtin_amdgcn_mfma_f32_16x16x32_bf16(ah[i], bfr[j], acc[i][j], 0, 0, 0);
        acc[i][j] = __builtin_amdgcn_mfma_f32_16x16x32_bf16(al[i], bfr[j], acc[i][j], 0, 0, 0);
      }
    __syncthreads();
    cur ^= 1;
  }

  // scores store
  #pragma unroll
  for (int i = 0; i < 4; ++i)
    #pragma unroll
    for (int j = 0; j < 4; ++j)
      #pragma unroll
      for (int r = 0; r < 4; ++r)
        scores[((size_t)(b * 128) + wm + i * 16 + l4 * 4 + r) * 4096 + nb + wn + j * 16 + l15] =
            acc[i][j][r];

  // Softmax partials for this 128s x 128n tile.
  const int nh = wn >> 6;
  float cm[4][4];
  #pragma unroll
  for (int i = 0; i < 4; ++i)
    #pragma unroll
    for (int r = 0; r < 4; ++r) {
      float v = fmaxf(fmaxf(acc[i][0][r], acc[i][1][r]),
                      fmaxf(acc[i][2][r], acc[i][3][r]));
      v = fmaxf(v, __shfl_xor(v, 1));
      v = fmaxf(v, __shfl_xor(v, 2));
      v = fmaxf(v, __shfl_xor(v, 4));
      v = fmaxf(v, __shfl_xor(v, 8));
      if (l15 == 0) SmP[(wm + i * 16 + l4 * 4 + r) * 2 + nh] = v;
    }
  __syncthreads();
  #pragma unroll
  for (int i = 0; i < 4; ++i)
    #pragma unroll
    for (int r = 0; r < 4; ++r) {
      int s = wm + i * 16 + l4 * 4 + r;
      cm[i][r] = fmaxf(SmP[s * 2], SmP[s * 2 + 1]);
    }
  #pragma unroll
  for (int i = 0; i < 4; ++i)
    #pragma unroll
    for (int r = 0; r < 4; ++r) {
      float s0 = __expf(acc[i][0][r] - cm[i][r]) + __expf(acc[i][1][r] - cm[i][r]) +
                 __expf(acc[i][2][r] - cm[i][r]) + __expf(acc[i][3][r] - cm[i][r]);
      s0 += __shfl_xor(s0, 1);
      s0 += __shfl_xor(s0, 2);
      s0 += __shfl_xor(s0, 4);
      s0 += __shfl_xor(s0, 8);
      if (l15 == 0) SsP[(wm + i * 16 + l4 * 4 + r) * 2 + nh] = s0;
    }
  __syncthreads();
  if (tid < 128) {
    size_t pidx = ((size_t)(b * 128) + tid) * 32 + ntile;
    pmax_g[pidx] = fmaxf(SmP[tid * 2], SmP[tid * 2 + 1]);
    psum_g[pidx] = SsP[tid * 2] + SsP[tid * 2 + 1];
  }
}

// ---------------------------------------------------------------------------
// K5E: combine per-tile partials -> (m, 1/sum) per (b,s), then
// Eb[b,n,s] = bf16( exp(scores[b,s,n]-m) * linv )  (transpose + exp)
// ---------------------------------------------------------------------------
__global__ __launch_bounds__(256) void k5e_expT(
    const float* __restrict__ scores, const float* __restrict__ pmax_g,
    const float* __restrict__ psum_g, unsigned short* __restrict__ Eb)
{
  const int nt = blockIdx.x, b = blockIdx.y, tid = threadIdx.x;
  __shared__ float L[128 * 68];
  __shared__ float sm[128], sl[128];
  if (tid < 128) {
    float M = 0.f, linv = 0.f;
    if (tid < 110) {
      const float* pm = pmax_g + ((size_t)(b * 128) + tid) * 32;
      const float* ps = psum_g + ((size_t)(b * 128) + tid) * 32;
      M = -3.4e38f;
      #pragma unroll
      for (int t = 0; t < 32; ++t) M = fmaxf(M, pm[t]);
      float S = 0.f;
      #pragma unroll
      for (int t = 0; t < 32; ++t) S += ps[t] * __expf(pm[t] - M);
      linv = 1.f / S;
    }
    sm[tid] = M; sl[tid] = linv;
  }
  #pragma unroll
  for (int j = 0; j < 8; ++j) {
    int flat = tid + 256 * j;
    int s = flat >> 4, n4 = (flat & 15) << 2;
    *(float4*)&L[s * 68 + n4] =
        *(const float4*)(scores + ((size_t)(b * 128) + s) * 4096 + nt * 64 + n4);
  }
  __syncthreads();
  int n = tid >> 2, sq = (tid & 3) * 32;
  unsigned ub[16];
  #pragma unroll
  for (int k = 0; k < 32; k += 2) {
    float e0 = __expf(L[(sq + k) * 68 + n] - sm[sq + k]) * sl[sq + k];
    float e1 = __expf(L[(sq + k + 1) * 68 + n] - sm[sq + k + 1]) * sl[sq + k + 1];
    ub[k >> 1] = pack2(e0, e1);
  }
  uint4* dst = (uint4*)(Eb + ((size_t)(b * 4096) + nt * 64 + n) * 128 + sq);
  #pragma unroll
  for (int j = 0; j < 4; ++j)
    dst[j] = make_uint4(ub[4 * j], ub[4 * j + 1], ub[4 * j + 2], ub[4 * j + 3]);
}

// ---------------------------------------------------------------------------
// K6: out[b,o,n] = sum_s Vb[b,o,s] * Eb[b,n,s] + x[b,o,n]
// Whole K=128 staged at once (8 DMA slabs, ONE barrier); x prefetched into
// VGPRs while the LDS-DMA is in flight so the residual-add never stalls.
// ---------------------------------------------------------------------------
__global__ __launch_bounds__(256) void k6_out(
    const unsigned short* __restrict__ Eb, const unsigned short* __restrict__ Vb,
    const float* __restrict__ x, float* __restrict__ out)
{
  const int tid = threadIdx.x;
  const int nb = blockIdx.x * 128;
  const int mb = blockIdx.y * 128;
  const int b = blockIdx.z;
  const int lane = tid & 63, wv = tid >> 6;
  const int wm = (wv & 1) * 64, wn = (wv >> 1) * 64;
  const int l15 = lane & 15, l4 = lane >> 4;
  __shared__ __align__(16) unsigned short SA[4][4096];   // 32 KB
  __shared__ __align__(16) unsigned short SB[4][4096];   // 32 KB

  #pragma unroll
  for (int h = 0; h < 4; ++h)
    #pragma unroll
    for (int p = 0; p < 2; ++p) {
      int chunk = (wv * 2 + p) * 64 + lane;
      int row = chunk >> 2, c16 = chunk & 3;
      gl_lds16(Vb + ((size_t)(b * 512) + mb + row) * 128 + h * 32 + c16 * 8,
               &SA[h][(wv * 2 + p) * 512]);
      gl_lds16(Eb + ((size_t)(b * 4096) + nb + row) * 128 + h * 32 + c16 * 8,
               &SB[h][(wv * 2 + p) * 512]);
    }

  float xr[4][4][4];
  #pragma unroll
  for (int i = 0; i < 4; ++i)
    #pragma unroll
    for (int j = 0; j < 4; ++j)
      #pragma unroll
      for (int r = 0; r < 4; ++r)
        xr[i][j][r] = x[((size_t)(b * 512) + mb + wm + i * 16 + l4 * 4 + r) * 4096 +
                        nb + wn + j * 16 + l15];

  f32x4 acc[4][4];
  #pragma unroll
  for (int i = 0; i < 4; ++i)
    #pragma unroll
    for (int j = 0; j < 4; ++j) acc[i][j] = f32x4{0.f, 0.f, 0.f, 0.f};

  __syncthreads();
  #pragma unroll
  for (int h = 0; h < 4; ++h) {
    bf16x8 af[4], bfr[4];
    #pragma unroll
    for (int i = 0; i < 4; ++i)
      af[i] = *(const bf16x8*)&SA[h][(wm + i * 16 + l15) * 32 + l4 * 8];
    #pragma unroll
    for (int j = 0; j < 4; ++j)
      bfr[j] = *(const bf16x8*)&SB[h][(wn + j * 16 + l15) * 32 + l4 * 8];
    #pragma unroll
    for (int i = 0; i < 4; ++i)
      #pragma unroll
      for (int j = 0; j < 4; ++j)
        acc[i][j] = __builtin_amdgcn_mfma_f32_16x16x32_bf16(af[i], bfr[j], acc[i][j], 0, 0, 0);
  }
  #pragma unroll
  for (int i = 0; i < 4; ++i)
    #pragma unroll
    for (int j = 0; j < 4; ++j)
      #pragma unroll
      for (int r = 0; r < 4; ++r) {
        int o = mb + wm + i * 16 + l4 * 4 + r;
        size_t idx = ((size_t)(b * 512) + o) * 4096 + nb + wn + j * 16 + l15;
        out[idx] = acc[i][j][r] + xr[i][j][r];
      }
}

// ---------------------------------------------------------------------------
extern "C" void kernel_launch(void* const* d_in, const int* in_sizes, int n_in,
                              void* d_out, int out_size, void* d_ws, size_t ws_size,
                              hipStream_t stream)
{
  (void)in_sizes; (void)n_in; (void)out_size; (void)ws_size;
  const float* x       = (const float*)d_in[0];
  const float* y       = (const float*)d_in[1];
  const float* w_phi   = (const float*)d_in[2];
  const float* w_theta = (const float*)d_in[3];
  const float* w_g     = (const float*)d_in[4];
  const float* w_mask  = (const float*)d_in[5];
  float* out = (float*)d_out;

  // Workspace: 130,039,808 B total.
  // Region A (67108864): yT, later overwritten by xT (after k1f).
  // Region B (54525952): Rbuf (18.9MB) -> scores (33.5MB) | Eb (16.8MB) |
  //   tail slot: wTG (512KB, pw->k1f) / Vb (2MB, k3->k6) + partials (512KB,
  //   k4->k5e) in the 2MB slack after Vb.
  // Region C (8404992): Pt, Pg, Kth, Ktl (mbuf/lbuf slots now unused).
  char* ws = (char*)d_ws;
  unsigned short* yT = (unsigned short*)ws;
  unsigned short* xT = yT;                                    // alias: after k1f
  char* B0 = ws + 67108864;
  unsigned short* Rbuf = (unsigned short*)B0;                 // 18874368 B
  float* scores = (float*)B0;                                 // 33554432 B (after k2)
  unsigned short* Eb = (unsigned short*)(B0 + 33554432);      // 16777216 B
  unsigned short* wTG = (unsigned short*)(B0 + 50331648);     // 524288 B (pw->k1f)
  unsigned short* Vb  = (unsigned short*)(B0 + 50331648);     // 2097152 B (k3->k6)
  float* pmax_g = (float*)(B0 + 52428800);                    // 262144 B (k4->k5e)
  float* psum_g = (float*)(B0 + 52690944);                    // 262144 B (k4->k5e)
  char* C0 = B0 + 54525952;
  float* Pt = (float*)C0;                                     // 2097152
  float* Pg = (float*)(C0 + 2097152);                         // 2097152
  unsigned short* Kth = (unsigned short*)(C0 + 4194304);      // 2097152
  unsigned short* Ktl = (unsigned short*)(C0 + 6291456);      // 2097152

  p0w_transpose<<<dim3(64, 8, 17), 256, 0, stream>>>(y, yT, w_theta, w_g, wTG);
  k1f_conv_pool<<<dim3(128, 16), 256, 0, stream>>>(yT, wTG, Rbuf);
  k2_pool_final<<<dim3(128, 16), 256, 0, stream>>>(Rbuf, Pt, Pg);
  k3_fused<<<dim3(8, 16, 2), 256, 0, stream>>>(Pt, Pg, w_phi, w_mask, Kth, Ktl, Vb);
  p0w_transpose<<<dim3(64, 8, 16), 256, 0, stream>>>(x, xT, w_theta, w_g, wTG);
  k4_scores<<<dim3(32, 16), 256, 0, stream>>>(xT, Kth, Ktl, scores, pmax_g, psum_g);
  k5e_expT<<<dim3(64, 16), 256, 0, stream>>>(scores, pmax_g, psum_g, Eb);
  k6_out<<<dim3(32, 4, 16), 256, 0, stream>>>(Eb, Vb, x, out);
}

// Round 4
// 490.442 us; speedup vs baseline: 1.1274x; 1.0220x over previous
//
#include <hip/hip_runtime.h>

#define DI __device__ __forceinline__

typedef __attribute__((ext_vector_type(8))) __bf16 bf16x8;
typedef __attribute__((ext_vector_type(4))) float f32x4;

DI unsigned short f2bf(float x) {
  union { float f; unsigned u; } v; v.f = x;
  unsigned r = v.u + 0x7fffu + ((v.u >> 16) & 1u);
  return (unsigned short)(r >> 16);
}
DI float bf2f(unsigned short h) {
  union { unsigned u; float f; } v; v.u = ((unsigned)h) << 16;
  return v.f;
}
DI unsigned pack2(float a, float b) {
  return (unsigned)f2bf(a) | (((unsigned)f2bf(b)) << 16);
}

// Async global->LDS DMA, 16B per lane. LDS dest is wave-uniform base +
// lane*16; global src is per-lane. Drained by the vmcnt(0) the compiler
// emits before s_barrier (__syncthreads).
DI void gl_lds16(const void* g, void* l) {
  __builtin_amdgcn_global_load_lds(
      (const __attribute__((address_space(1))) void*)g,
      (__attribute__((address_space(3))) void*)l, 16, 0, 0);
}

// ---------------------------------------------------------------------------
// P0W: transpose-convert y [b][512 c][4096 n] f32 -> yT [b][4096 n][512 c]
// bf16 (z<16), plus one-time weight convert w_theta|w_g -> bf16 wTG on the
// z==16 slice. (x is no longer pre-transposed: k4 transposes inline.)
// ---------------------------------------------------------------------------
__global__ __launch_bounds__(256) void p0w_transpose(
    const float* __restrict__ src, unsigned short* __restrict__ dst,
    const float* __restrict__ w_theta, const float* __restrict__ w_g,
    unsigned short* __restrict__ wTG)
{
  if (blockIdx.z == 16) {                       // pw slice
    if (blockIdx.y < 2) {
      int e = ((blockIdx.y * 64 + blockIdx.x) * 256 + threadIdx.x) * 8;
      const float* s = (e < 131072) ? (w_theta + e) : (w_g + (e - 131072));
      float4 a = *(const float4*)s;
      float4 c = *(const float4*)(s + 4);
      uint4 u;
      u.x = pack2(a.x, a.y); u.y = pack2(a.z, a.w);
      u.z = pack2(c.x, c.y); u.w = pack2(c.z, c.w);
      *(uint4*)(wTG + e) = u;
    }
    return;
  }
  const int n0 = blockIdx.x * 64, c0 = blockIdx.y * 64, b = blockIdx.z;
  const int tid = threadIdx.x;
  __shared__ float T[64 * 65];
  #pragma unroll
  for (int p = 0; p < 4; ++p) {
    int r = p * 16 + (tid >> 4);
    int n4 = (tid & 15) << 2;
    *(float4*)&T[r * 65 + n4] =
        *(const float4*)(src + ((size_t)(b * 512 + c0 + r)) * 4096 + n0 + n4);
  }
  __syncthreads();
  int n = tid >> 2, cc = (tid & 3) * 16;
  unsigned u[8];
  #pragma unroll
  for (int j = 0; j < 16; j += 2)
    u[j >> 1] = pack2(T[(cc + j) * 65 + n], T[(cc + j + 1) * 65 + n]);
  unsigned short* d = dst + ((size_t)(b * 4096 + n0 + n)) * 512 + c0 + cc;
  *(uint4*)(d) = make_uint4(u[0], u[1], u[2], u[3]);
  *(uint4*)(d + 8) = make_uint4(u[4], u[5], u[6], u[7]);
}

// ---------------------------------------------------------------------------
// K1F: conv (theta|g) 128o x 128n tile via bf16 MFMA, both operands DMA'd,
// 2-phase double-buffer (one barrier/K-step). Fused SPP pooling epilogue.
// ---------------------------------------------------------------------------
__constant__ int c_RS[18] = {0, 0,21,42, 0,10,21,32,42,53, 0,8,16,24,32,40,48,56};
__constant__ int c_RE[18] = {64, 22,43,64, 11,22,32,43,54,64, 8,16,24,32,40,48,56,64};

__global__ __launch_bounds__(256) void k1f_conv_pool(
    const unsigned short* __restrict__ yT, const unsigned short* __restrict__ wTG,
    unsigned short* __restrict__ Rbuf)
{
  const int tid = threadIdx.x;
  const int id = blockIdx.x;
  const int tile = (id & 7) * 16 + (id >> 3);   // XCD-chunked, bijective
  const int mb = (tile & 3) * 128;
  const int nbt = tile >> 2;
  const int nb = nbt * 128;
  const int b  = blockIdx.y;
  const int lane = tid & 63, wv = tid >> 6;
  const int wm = (wv & 1) * 64, wn = (wv >> 1) * 64;
  const int l15 = lane & 15, l4 = lane >> 4;

  __shared__ __align__(16) char smem[33280];    // dbuf staging 32KB | epi 33.3KB
  float* P = (float*)smem;

  f32x4 acc[4][4];
  #pragma unroll
  for (int i = 0; i < 4; ++i)
    #pragma unroll
    for (int j = 0; j < 4; ++j) acc[i][j] = f32x4{0.f, 0.f, 0.f, 0.f};

  auto stage = [&](int buf, int kb) {
    unsigned short* As = (unsigned short*)(smem + buf * 16384);
    unsigned short* Bs = As + 4096;
    #pragma unroll
    for (int p = 0; p < 2; ++p) {
      int chunk = (wv * 2 + p) * 64 + lane;     // 16B chunk id, 0..511
      int row = chunk >> 2, c16 = chunk & 3;
      gl_lds16(wTG + ((size_t)(mb + row)) * 512 + kb + c16 * 8,
               As + (wv * 2 + p) * 512);
      gl_lds16(yT + ((size_t)(b * 4096 + nb + row)) * 512 + kb + c16 * 8,
               Bs + (wv * 2 + p) * 512);
    }
  };

  stage(0, 0);
  __syncthreads();
  int cur = 0;
  for (int t = 0; t < 16; ++t) {
    if (t < 15) stage(cur ^ 1, (t + 1) * 32);
    const unsigned short* As = (const unsigned short*)(smem + cur * 16384);
    const unsigned short* Bs = As + 4096;
    bf16x8 af[4], bfr[4];
    #pragma unroll
    for (int i = 0; i < 4; ++i)
      af[i] = *(const bf16x8*)&As[(wm + i * 16 + l15) * 32 + l4 * 8];
    #pragma unroll
    for (int j = 0; j < 4; ++j)
      bfr[j] = *(const bf16x8*)&Bs[(wn + j * 16 + l15) * 32 + l4 * 8];
    #pragma unroll
    for (int i = 0; i < 4; ++i)
      #pragma unroll
      for (int j = 0; j < 4; ++j)
        acc[i][j] = __builtin_amdgcn_mfma_f32_16x16x32_bf16(af[i], bfr[j], acc[i][j], 0, 0, 0);
    __syncthreads();
    cur ^= 1;
  }

  // Fused pooling epilogue: two passes (n-halves = image rows h, h+1).
  const int hloc = wv >> 1;
  #pragma unroll
  for (int pass = 0; pass < 2; ++pass) {
    __syncthreads();
    if (hloc == pass) {
      #pragma unroll
      for (int i = 0; i < 4; ++i)
        #pragma unroll
        for (int j = 0; j < 4; ++j)
          #pragma unroll
          for (int r = 0; r < 4; ++r)
            P[(wm + i * 16 + l4 * 4 + r) * 65 + j * 16 + l15] = acc[i][j][r];
    }
    __syncthreads();
    const int o = tid & 127;
    size_t rbase = (((size_t)(b * 64 + nbt * 2 + pass)) * 18) * 512 + mb + o;
    if (tid < 128) {
      float b0 = -3.4e38f, b1 = b0, b2 = b0, b3 = b0;
      #pragma unroll
      for (int w = 0; w < 64; ++w) {
        float v = P[o * 65 + w];
        b0 = fmaxf(b0, v);
        if (w < 22) b1 = fmaxf(b1, v);
        if (w >= 21 && w < 43) b2 = fmaxf(b2, v);
        if (w >= 42) b3 = fmaxf(b3, v);
      }
      Rbuf[rbase]           = f2bf(b0);
      Rbuf[rbase + 512]     = f2bf(b1);
      Rbuf[rbase + 2 * 512] = f2bf(b2);
      Rbuf[rbase + 3 * 512] = f2bf(b3);
    } else {
      float s6[6], s8[8];
      #pragma unroll
      for (int i = 0; i < 6; ++i) s6[i] = -3.4e38f;
      #pragma unroll
      for (int i = 0; i < 8; ++i) s8[i] = -3.4e38f;
      constexpr int R6S[6] = {0, 10, 21, 32, 42, 53};
      constexpr int R6E[6] = {11, 22, 32, 43, 54, 64};
      #pragma unroll
      for (int w = 0; w < 64; ++w) {
        float v = P[o * 65 + w];
        #pragma unroll
        for (int i = 0; i < 6; ++i)
          if (w >= R6S[i] && w < R6E[i]) s6[i] = fmaxf(s6[i], v);
        s8[w >> 3] = fmaxf(s8[w >> 3], v);
      }
      #pragma unroll
      for (int i = 0; i < 6; ++i) Rbuf[rbase + (size_t)(4 + i) * 512] = f2bf(s6[i]);
      #pragma unroll
      for (int i = 0; i < 8; ++i) Rbuf[rbase + (size_t)(10 + i) * 512] = f2bf(s8[i]);
    }
  }
}

// ---------------------------------------------------------------------------
// K2F: reduce Rbuf over h within each pyramid h-bin -> Pt/Pg [b][128 s][256].
// ---------------------------------------------------------------------------
__global__ __launch_bounds__(256) void k2_pool_final(
    const unsigned short* __restrict__ Rbuf, float* __restrict__ Pt,
    float* __restrict__ Pg)
{
  const int s = blockIdx.x, b = blockIdx.y, tid = threadIdx.x;
  size_t obase = ((size_t)(b * 128) + s) * 256 + tid;
  if (s >= 110) { Pt[obase] = 0.f; Pg[obase] = 0.f; return; }
  int he, wb;
  if (s == 0)      { he = 0; wb = 0; }
  else if (s < 10) { int i = s - 1;  he = 1 + i / 3;  wb = 1 + i % 3; }
  else if (s < 46) { int i = s - 10; he = 4 + i / 6;  wb = 4 + i % 6; }
  else             { int i = s - 46; he = 10 + i / 8; wb = 10 + i % 8; }
  float m0 = -3.4e38f, m1 = -3.4e38f;
  int e = c_RE[he];
  for (int h = c_RS[he]; h < e; ++h) {
    const unsigned short* r = Rbuf + (((size_t)(b * 64 + h)) * 18 + wb) * 512;
    m0 = fmaxf(m0, bf2f(r[tid]));
    m1 = fmaxf(m1, bf2f(r[tid + 256]));
  }
  Pt[obase] = m0;
  Pg[obase] = m1;
}

// ---------------------------------------------------------------------------
// K3 (fused kmat+vmat, blockIdx.z selects):
//  z=0: Kt[b,s,c] = sum_ic w_phi[ic,c]*Pt[b,s,ic] -> hi/lo bf16 split
//  z=1: Vb[b,o,s] = bf16( sum_ic w_mask[o,ic]*Pg[b,s,ic] )
// ---------------------------------------------------------------------------
__global__ __launch_bounds__(256) void k3_fused(
    const float* __restrict__ Pt, const float* __restrict__ Pg,
    const float* __restrict__ w_phi, const float* __restrict__ w_mask,
    unsigned short* __restrict__ Kth, unsigned short* __restrict__ Ktl,
    unsigned short* __restrict__ Vb)
{
  __shared__ __align__(16) char sm3[51200];
  const int tid = threadIdx.x;
  const int tx = tid & 15, ty = tid >> 4;
  const int b = blockIdx.y;
  if (blockIdx.z == 0) {
    const int ct = blockIdx.x;
    const int c0 = tx * 4, s0 = ty * 8;
    float* Ls = (float*)sm3;            // [128][64]
    float* Ws = Ls + 128 * 64;          // [64][68]
    float acc[8][4] = {};
    for (int kc = 0; kc < 256; kc += 64) {
      #pragma unroll
      for (int j = 0; j < 8; ++j) {
        int flat = tid + 256 * j;
        int row = flat >> 4, k4 = (flat & 15) << 2;
        *(float4*)&Ls[row * 64 + k4] =
            *(const float4*)(Pt + ((size_t)(b * 128) + row) * 256 + kc + k4);
      }
      #pragma unroll
      for (int j = 0; j < 4; ++j) {
        int flat = tid + 256 * j;
        int row = flat >> 4, c4 = (flat & 15) << 2;
        *(float4*)&Ws[row * 68 + c4] =
            *(const float4*)(w_phi + (size_t)(kc + row) * 512 + ct * 64 + c4);
      }
      __syncthreads();
      for (int k = 0; k < 64; k += 4) {
        float4 wv[4];
        #pragma unroll
        for (int kk = 0; kk < 4; ++kk) wv[kk] = *(const float4*)&Ws[(k + kk) * 68 + c0];
        #pragma unroll
        for (int i = 0; i < 8; ++i) {
          float4 a = *(const float4*)&Ls[(s0 + i) * 64 + k];
          const float* ap = (const float*)&a;
          #pragma unroll
          for (int kk = 0; kk < 4; ++kk) {
            const float* wp = (const float*)&wv[kk];
            acc[i][0] += ap[kk] * wp[0];
            acc[i][1] += ap[kk] * wp[1];
            acc[i][2] += ap[kk] * wp[2];
            acc[i][3] += ap[kk] * wp[3];
          }
        }
      }
      __syncthreads();
    }
    #pragma unroll
    for (int i = 0; i < 8; ++i) {
      unsigned short hi[4]; float lo[4];
      #pragma unroll
      for (int j = 0; j < 4; ++j) { hi[j] = f2bf(acc[i][j]); lo[j] = acc[i][j] - bf2f(hi[j]); }
      size_t base = ((size_t)(b * 128) + s0 + i) * 512 + ct * 64 + c0;
      uint2 uh; uh.x = (unsigned)hi[0] | ((unsigned)hi[1] << 16);
      uh.y = (unsigned)hi[2] | ((unsigned)hi[3] << 16);
      uint2 ul; ul.x = pack2(lo[0], lo[1]); ul.y = pack2(lo[2], lo[3]);
      *(uint2*)&Kth[base] = uh;
      *(uint2*)&Ktl[base] = ul;
    }
  } else {
    const int ot = blockIdx.x;
    const int o0 = ty * 4;
    float* Ws = (float*)sm3;            // [64][64]
    float* Ps = Ws + 64 * 64;           // [128][68]
    float acc[4][8] = {};
    for (int kc = 0; kc < 256; kc += 64) {
      #pragma unroll
      for (int j = 0; j < 4; ++j) {
        int flat = tid + 256 * j;
        int row = flat >> 4, k4 = (flat & 15) << 2;
        *(float4*)&Ws[row * 64 + k4] =
            *(const float4*)(w_mask + (size_t)(ot * 64 + row) * 256 + kc + k4);
      }
      #pragma unroll
      for (int j = 0; j < 8; ++j) {
        int flat = tid + 256 * j;
        int row = flat >> 4, k4 = (flat & 15) << 2;
        *(float4*)&Ps[row * 68 + k4] =
            *(const float4*)(Pg + ((size_t)(b * 128) + row) * 256 + kc + k4);
      }
      __syncthreads();
      for (int k = 0; k < 64; k += 4) {
        float4 wv[4];
        #pragma unroll
        for (int i = 0; i < 4; ++i) wv[i] = *(const float4*)&Ws[(o0 + i) * 64 + k];
        #pragma unroll
        for (int jj = 0; jj < 8; ++jj) {
          float4 pv = *(const float4*)&Ps[(tx + 16 * jj) * 68 + k];
          const float* pp = (const float*)&pv;
          #pragma unroll
          for (int i = 0; i < 4; ++i) {
            const float* wp = (const float*)&wv[i];
            #pragma unroll
            for (int kk = 0; kk < 4; ++kk) acc[i][jj] += wp[kk] * pp[kk];
          }
        }
      }
      __syncthreads();
    }
    #pragma unroll
    for (int i = 0; i < 4; ++i)
      #pragma unroll
      for (int jj = 0; jj < 8; ++jj)
        Vb[((size_t)(b * 512) + ot * 64 + o0 + i) * 128 + tx + 16 * jj] =
            f2bf(acc[i][jj]);
  }
}

// ---------------------------------------------------------------------------
// K4: scoresT[b,n,s] = sum_c Kt[b,s,c]*x[b,c,n]; Kt hi/lo split (2 MFMAs).
// A (Kth/Ktl) via global_load_lds; B staged from RAW x f32 with inline
// transpose-convert (each thread owns one n-column, 16 c-dwords -> pack ->
// 2x ds_write_b128 into padded [128][40] slab). x-loads issued at phase
// start ride under MFMA (T14); one barrier per K-step. Output written
// TRANSPOSED [n][s] so stores are float4 and k5e needs no LDS transpose.
// Epilogue emits per-(s, n-tile) softmax partials (max, sum-exp).
// ---------------------------------------------------------------------------
__global__ __launch_bounds__(256) void k4_scores(
    const float* __restrict__ x, const unsigned short* __restrict__ Kth,
    const unsigned short* __restrict__ Ktl, float* __restrict__ scoresT,
    float* __restrict__ pmax_g, float* __restrict__ psum_g)
{
  const int tid = threadIdx.x;
  const int ntile = blockIdx.x;
  const int nb = ntile * 128;
  const int b = blockIdx.y;
  const int lane = tid & 63, wv = tid >> 6;
  const int wm = (wv & 1) * 64, wn = (wv >> 1) * 64;
  const int l15 = lane & 15, l4 = lane >> 4;
  // per buffer: Ah 8192B | Al 8192B | Bs [128][40] ush = 10240B -> 26624B
  __shared__ __align__(16) char smem4[2 * 26624];
  __shared__ float SmP[256], SsP[256];

  const int xn = tid & 127, xh = tid >> 7;       // n-column, c-half (16 c)
  const float* xcol = x + ((size_t)(b * 512 + xh * 16)) * 4096 + nb + xn;

  f32x4 acc[4][4];
  #pragma unroll
  for (int i = 0; i < 4; ++i)
    #pragma unroll
    for (int j = 0; j < 4; ++j) acc[i][j] = f32x4{0.f, 0.f, 0.f, 0.f};

  float xr[16];
  auto xload = [&](int kb) {
    const float* p = xcol + (size_t)kb * 4096;
    #pragma unroll
    for (int k = 0; k < 16; ++k) xr[k] = p[(size_t)k * 4096];
  };
  auto dmaA = [&](int buf, int kb) {
    unsigned short* Ah = (unsigned short*)(smem4 + buf * 26624);
    unsigned short* Al = Ah + 4096;
    #pragma unroll
    for (int p = 0; p < 2; ++p) {
      int chunk = (wv * 2 + p) * 64 + lane;
      int row = chunk >> 2, c16 = chunk & 3;
      size_t g = ((size_t)(b * 128) + row) * 512 + kb + c16 * 8;
      gl_lds16(Kth + g, Ah + (wv * 2 + p) * 512);
      gl_lds16(Ktl + g, Al + (wv * 2 + p) * 512);
    }
  };
  auto bwrite = [&](int buf) {
    unsigned short* Bs = (unsigned short*)(smem4 + buf * 26624 + 16384);
    unsigned u[8];
    #pragma unroll
    for (int k = 0; k < 16; k += 2) u[k >> 1] = pack2(xr[k], xr[k + 1]);
    uint4* d = (uint4*)&Bs[xn * 40 + xh * 16];
    d[0] = make_uint4(u[0], u[1], u[2], u[3]);
    d[1] = make_uint4(u[4], u[5], u[6], u[7]);
  };

  xload(0);
  dmaA(0, 0);
  bwrite(0);
  __syncthreads();
  int cur = 0;
  for (int t = 0; t < 16; ++t) {
    if (t < 15) { xload((t + 1) * 32); dmaA(cur ^ 1, (t + 1) * 32); }
    const unsigned short* Ah = (const unsigned short*)(smem4 + cur * 26624);
    const unsigned short* Al = Ah + 4096;
    const unsigned short* Bs = (const unsigned short*)(smem4 + cur * 26624 + 16384);
    bf16x8 ah[4], al[4], bfr[4];
    #pragma unroll
    for (int i = 0; i < 4; ++i) {
      ah[i] = *(const bf16x8*)&Ah[(wm + i * 16 + l15) * 32 + l4 * 8];
      al[i] = *(const bf16x8*)&Al[(wm + i * 16 + l15) * 32 + l4 * 8];
    }
    #pragma unroll
    for (int j = 0; j < 4; ++j)
      bfr[j] = *(const bf16x8*)&Bs[(wn + j * 16 + l15) * 40 + l4 * 8];
    #pragma unroll
    for (int i = 0; i < 4; ++i)
      #pragma unroll
      for (int j = 0; j < 4; ++j) {
        acc[i][j] = __builtin_amdgcn_mfma_f32_16x16x32_bf16(ah[i], bfr[j], acc[i][j], 0, 0, 0);
        acc[i][j] = __builtin_amdgcn_mfma_f32_16x16x32_bf16(al[i], bfr[j], acc[i][j], 0, 0, 0);
      }
    if (t < 15) bwrite(cur ^ 1);
    __syncthreads();
    cur ^= 1;
  }

  // scoresT store: n row = nb+wn+j*16+l15, s base = wm+i*16+l4*4 (float4 in s)
  #pragma unroll
  for (int i = 0; i < 4; ++i)
    #pragma unroll
    for (int j = 0; j < 4; ++j)
      *(float4*)(scoresT + ((size_t)(b * 4096) + nb + wn + j * 16 + l15) * 128 +
                 wm + i * 16 + l4 * 4) = *(float4*)&acc[i][j];

  // Softmax partials for this 128s x 128n tile.
  const int nh = wn >> 6;
  float cm[4][4];
  #pragma unroll
  for (int i = 0; i < 4; ++i)
    #pragma unroll
    for (int r = 0; r < 4; ++r) {
      float v = fmaxf(fmaxf(acc[i][0][r], acc[i][1][r]),
                      fmaxf(acc[i][2][r], acc[i][3][r]));
      v = fmaxf(v, __shfl_xor(v, 1));
      v = fmaxf(v, __shfl_xor(v, 2));
      v = fmaxf(v, __shfl_xor(v, 4));
      v = fmaxf(v, __shfl_xor(v, 8));
      if (l15 == 0) SmP[(wm + i * 16 + l4 * 4 + r) * 2 + nh] = v;
    }
  __syncthreads();
  #pragma unroll
  for (int i = 0; i < 4; ++i)
    #pragma unroll
    for (int r = 0; r < 4; ++r) {
      int s = wm + i * 16 + l4 * 4 + r;
      cm[i][r] = fmaxf(SmP[s * 2], SmP[s * 2 + 1]);
    }
  #pragma unroll
  for (int i = 0; i < 4; ++i)
    #pragma unroll
    for (int r = 0; r < 4; ++r) {
      float s0 = __expf(acc[i][0][r] - cm[i][r]) + __expf(acc[i][1][r] - cm[i][r]) +
                 __expf(acc[i][2][r] - cm[i][r]) + __expf(acc[i][3][r] - cm[i][r]);
      s0 += __shfl_xor(s0, 1);
      s0 += __shfl_xor(s0, 2);
      s0 += __shfl_xor(s0, 4);
      s0 += __shfl_xor(s0, 8);
      if (l15 == 0) SsP[(wm + i * 16 + l4 * 4 + r) * 2 + nh] = s0;
    }
  __syncthreads();
  if (tid < 128) {
    size_t pidx = ((size_t)(b * 128) + tid) * 32 + ntile;
    pmax_g[pidx] = fmaxf(SmP[tid * 2], SmP[tid * 2 + 1]);
    psum_g[pidx] = SsP[tid * 2] + SsP[tid * 2 + 1];
  }
}

// ---------------------------------------------------------------------------
// K5E: combine per-tile partials -> (m, 1/sum) per (b,s), then stream
// Eb[b,n,s] = bf16( exp(scoresT[b,n,s]-m[s]) * linv[s] ).  Pure streaming:
// float4 in, uint2 out, no LDS transpose (scoresT already [n][s]).
// ---------------------------------------------------------------------------
__global__ __launch_bounds__(256) void k5e_exp(
    const float* __restrict__ scoresT, const float* __restrict__ pmax_g,
    const float* __restrict__ psum_g, unsigned short* __restrict__ Eb)
{
  const int b = blockIdx.y, tid = threadIdx.x;
  __shared__ float sm[128], sl[128];
  if (tid < 128) {
    float M = 0.f, linv = 0.f;
    if (tid < 110) {
      const float* pm = pmax_g + ((size_t)(b * 128) + tid) * 32;
      const float* ps = psum_g + ((size_t)(b * 128) + tid) * 32;
      M = -3.4e38f;
      #pragma unroll
      for (int t = 0; t < 32; ++t) M = fmaxf(M, pm[t]);
      float S = 0.f;
      #pragma unroll
      for (int t = 0; t < 32; ++t) S += ps[t] * __expf(pm[t] - M);
      linv = 1.f / S;
    }
    sm[tid] = M; sl[tid] = linv;
  }
  __syncthreads();
  const size_t base = (size_t)b * 4096 * 128;
  #pragma unroll
  for (int j = 0; j < 8; ++j) {
    int chunk = blockIdx.x * 2048 + j * 256 + tid;   // float4 id within b
    int sc = (chunk & 31) * 4;
    float4 v = *(const float4*)(scoresT + base + (size_t)chunk * 4);
    float e0 = __expf(v.x - sm[sc])     * sl[sc];
    float e1 = __expf(v.y - sm[sc + 1]) * sl[sc + 1];
    float e2 = __expf(v.z - sm[sc + 2]) * sl[sc + 2];
    float e3 = __expf(v.w - sm[sc + 3]) * sl[sc + 3];
    uint2 u; u.x = pack2(e0, e1); u.y = pack2(e2, e3);
    *(uint2*)(Eb + base + (size_t)chunk * 4) = u;
  }
}

// ---------------------------------------------------------------------------
// K6: out[b,o,n] = sum_s Vb[b,o,s] * Eb[b,n,s] + x[b,o,n]
// Whole K=128 staged at once (8 DMA slabs, ONE barrier); x prefetched into
// VGPRs while the LDS-DMA is in flight so the residual-add never stalls.
// ---------------------------------------------------------------------------
__global__ __launch_bounds__(256) void k6_out(
    const unsigned short* __restrict__ Eb, const unsigned short* __restrict__ Vb,
    const float* __restrict__ x, float* __restrict__ out)
{
  const int tid = threadIdx.x;
  const int nb = blockIdx.x * 128;
  const int mb = blockIdx.y * 128;
  const int b = blockIdx.z;
  const int lane = tid & 63, wv = tid >> 6;
  const int wm = (wv & 1) * 64, wn = (wv >> 1) * 64;
  const int l15 = lane & 15, l4 = lane >> 4;
  __shared__ __align__(16) unsigned short SA[4][4096];   // 32 KB
  __shared__ __align__(16) unsigned short SB[4][4096];   // 32 KB

  #pragma unroll
  for (int h = 0; h < 4; ++h)
    #pragma unroll
    for (int p = 0; p < 2; ++p) {
      int chunk = (wv * 2 + p) * 64 + lane;
      int row = chunk >> 2, c16 = chunk & 3;
      gl_lds16(Vb + ((size_t)(b * 512) + mb + row) * 128 + h * 32 + c16 * 8,
               &SA[h][(wv * 2 + p) * 512]);
      gl_lds16(Eb + ((size_t)(b * 4096) + nb + row) * 128 + h * 32 + c16 * 8,
               &SB[h][(wv * 2 + p) * 512]);
    }

  float xr[4][4][4];
  #pragma unroll
  for (int i = 0; i < 4; ++i)
    #pragma unroll
    for (int j = 0; j < 4; ++j)
      #pragma unroll
      for (int r = 0; r < 4; ++r)
        xr[i][j][r] = x[((size_t)(b * 512) + mb + wm + i * 16 + l4 * 4 + r) * 4096 +
                        nb + wn + j * 16 + l15];

  f32x4 acc[4][4];
  #pragma unroll
  for (int i = 0; i < 4; ++i)
    #pragma unroll
    for (int j = 0; j < 4; ++j) acc[i][j] = f32x4{0.f, 0.f, 0.f, 0.f};

  __syncthreads();
  #pragma unroll
  for (int h = 0; h < 4; ++h) {
    bf16x8 af[4], bfr[4];
    #pragma unroll
    for (int i = 0; i < 4; ++i)
      af[i] = *(const bf16x8*)&SA[h][(wm + i * 16 + l15) * 32 + l4 * 8];
    #pragma unroll
    for (int j = 0; j < 4; ++j)
      bfr[j] = *(const bf16x8*)&SB[h][(wn + j * 16 + l15) * 32 + l4 * 8];
    #pragma unroll
    for (int i = 0; i < 4; ++i)
      #pragma unroll
      for (int j = 0; j < 4; ++j)
        acc[i][j] = __builtin_amdgcn_mfma_f32_16x16x32_bf16(af[i], bfr[j], acc[i][j], 0, 0, 0);
  }
  #pragma unroll
  for (int i = 0; i < 4; ++i)
    #pragma unroll
    for (int j = 0; j < 4; ++j)
      #pragma unroll
      for (int r = 0; r < 4; ++r) {
        int o = mb + wm + i * 16 + l4 * 4 + r;
        size_t idx = ((size_t)(b * 512) + o) * 4096 + nb + wn + j * 16 + l15;
        out[idx] = acc[i][j][r] + xr[i][j][r];
      }
}

// ---------------------------------------------------------------------------
extern "C" void kernel_launch(void* const* d_in, const int* in_sizes, int n_in,
                              void* d_out, int out_size, void* d_ws, size_t ws_size,
                              hipStream_t stream)
{
  (void)in_sizes; (void)n_in; (void)out_size; (void)ws_size;
  const float* x       = (const float*)d_in[0];
  const float* y       = (const float*)d_in[1];
  const float* w_phi   = (const float*)d_in[2];
  const float* w_theta = (const float*)d_in[3];
  const float* w_g     = (const float*)d_in[4];
  const float* w_mask  = (const float*)d_in[5];
  float* out = (float*)d_out;

  // Workspace: 130,039,808 B total.
  // Region A (67108864): yT only (x no longer pre-transposed).
  // Region B (54525952): Rbuf (18.9MB) -> scoresT (33.5MB, after k2) |
  //   Eb (16.8MB) | tail: wTG (512KB, p0w->k1f) / Vb (2MB, k3->k6) +
  //   pmax/psum (512KB, k4->k5e).
  // Region C (8404992): Pt, Pg, Kth, Ktl.
  char* ws = (char*)d_ws;
  unsigned short* yT = (unsigned short*)ws;
  char* B0 = ws + 67108864;
  unsigned short* Rbuf = (unsigned short*)B0;                 // 18874368 B
  float* scoresT = (float*)B0;                                // 33554432 B (after k2)
  unsigned short* Eb = (unsigned short*)(B0 + 33554432);      // 16777216 B
  unsigned short* wTG = (unsigned short*)(B0 + 50331648);     // 524288 B (p0w->k1f)
  unsigned short* Vb  = (unsigned short*)(B0 + 50331648);     // 2097152 B (k3->k6)
  float* pmax_g = (float*)(B0 + 52428800);                    // 262144 B (k4->k5e)
  float* psum_g = (float*)(B0 + 52690944);                    // 262144 B (k4->k5e)
  char* C0 = B0 + 54525952;
  float* Pt = (float*)C0;                                     // 2097152
  float* Pg = (float*)(C0 + 2097152);                         // 2097152
  unsigned short* Kth = (unsigned short*)(C0 + 4194304);      // 2097152
  unsigned short* Ktl = (unsigned short*)(C0 + 6291456);      // 2097152

  p0w_transpose<<<dim3(64, 8, 17), 256, 0, stream>>>(y, yT, w_theta, w_g, wTG);
  k1f_conv_pool<<<dim3(128, 16), 256, 0, stream>>>(yT, wTG, Rbuf);
  k2_pool_final<<<dim3(128, 16), 256, 0, stream>>>(Rbuf, Pt, Pg);
  k3_fused<<<dim3(8, 16, 2), 256, 0, stream>>>(Pt, Pg, w_phi, w_mask, Kth, Ktl, Vb);
  k4_scores<<<dim3(32, 16), 256, 0, stream>>>(x, Kth, Ktl, scoresT, pmax_g, psum_g);
  k5e_exp<<<dim3(64, 16), 256, 0, stream>>>(scoresT, pmax_g, psum_g, Eb);
  k6_out<<<dim3(32, 4, 16), 256, 0, stream>>>(Eb, Vb, x, out);
}

// Round 5
// 487.442 us; speedup vs baseline: 1.1343x; 1.0062x over previous
//
#include <hip/hip_runtime.h>

#define DI __device__ __forceinline__

typedef __attribute__((ext_vector_type(8))) __bf16 bf16x8;
typedef __attribute__((ext_vector_type(4))) float f32x4;

DI unsigned short f2bf(float x) {
  union { float f; unsigned u; } v; v.f = x;
  unsigned r = v.u + 0x7fffu + ((v.u >> 16) & 1u);
  return (unsigned short)(r >> 16);
}
DI float bf2f(unsigned short h) {
  union { unsigned u; float f; } v; v.u = ((unsigned)h) << 16;
  return v.f;
}
DI unsigned pack2(float a, float b) {
  return (unsigned)f2bf(a) | (((unsigned)f2bf(b)) << 16);
}

// Async global->LDS DMA, 16B per lane. LDS dest is wave-uniform base +
// lane*16; global src is per-lane. Drained by the vmcnt(0) the compiler
// emits before s_barrier (__syncthreads).
DI void gl_lds16(const void* g, void* l) {
  __builtin_amdgcn_global_load_lds(
      (const __attribute__((address_space(1))) void*)g,
      (__attribute__((address_space(3))) void*)l, 16, 0, 0);
}

// ---------------------------------------------------------------------------
// PW: one-time weight convert [w_theta(256x512); w_g(256x512)] f32 -> bf16.
// ---------------------------------------------------------------------------
__global__ __launch_bounds__(256) void pw_conv(
    const float* __restrict__ w_theta, const float* __restrict__ w_g,
    unsigned short* __restrict__ wTG)
{
  int e = (blockIdx.x * 256 + threadIdx.x) * 8;
  const float* src = (e < 131072) ? (w_theta + e) : (w_g + (e - 131072));
  float4 a = *(const float4*)src;
  float4 c = *(const float4*)(src + 4);
  uint4 u;
  u.x = pack2(a.x, a.y); u.y = pack2(a.z, a.w);
  u.z = pack2(c.x, c.y); u.w = pack2(c.z, c.w);
  *(uint4*)(wTG + e) = u;
}

// ---------------------------------------------------------------------------
// K1F: conv (theta|g) 128o x 128n tile via bf16 MFMA DIRECTLY from raw y
// (no pre-transpose pass). A (wTG) via global_load_lds; B staged from y f32
// with inline transpose-convert, depth-2 register prefetch: xr for step t+2
// loads while step t+1's tile (loaded a phase ago) is packed+written BEFORE
// the MFMA block. One barrier per K-step. Fused SPP pooling epilogue.
// ---------------------------------------------------------------------------
__constant__ int c_RS[18] = {0, 0,21,42, 0,10,21,32,42,53, 0,8,16,24,32,40,48,56};
__constant__ int c_RE[18] = {64, 22,43,64, 11,22,32,43,54,64, 8,16,24,32,40,48,56,64};

__global__ __launch_bounds__(256) void k1f_conv_pool(
    const float* __restrict__ y, const unsigned short* __restrict__ wTG,
    unsigned short* __restrict__ Rbuf)
{
  const int tid = threadIdx.x;
  const int id = blockIdx.x;
  const int tile = (id & 7) * 16 + (id >> 3);   // XCD-chunked, bijective
  const int mb = (tile & 3) * 128;
  const int nbt = tile >> 2;
  const int nb = nbt * 128;
  const int b  = blockIdx.y;
  const int lane = tid & 63, wv = tid >> 6;
  const int wm = (wv & 1) * 64, wn = (wv >> 1) * 64;
  const int l15 = lane & 15, l4 = lane >> 4;

  // per buffer: As [128][32] 8192 B + Bs [128][40] 10240 B = 18432 B
  __shared__ __align__(16) char smem[2 * 18432];   // union: epi P 33280 B
  float* P = (float*)smem;

  const int xn = tid & 127, xh = tid >> 7;
  const float* ycol = y + ((size_t)(b * 512 + xh * 16)) * 4096 + nb + xn;

  f32x4 acc[4][4];
  #pragma unroll
  for (int i = 0; i < 4; ++i)
    #pragma unroll
    for (int j = 0; j < 4; ++j) acc[i][j] = f32x4{0.f, 0.f, 0.f, 0.f};

  float xrA[16], xrB[16];
  auto yload = [&](float* xr, int kb) {
    const float* p = ycol + (size_t)kb * 4096;
    #pragma unroll
    for (int k = 0; k < 16; ++k) xr[k] = p[(size_t)k * 4096];
  };
  auto dmaA = [&](int buf, int kb) {
    unsigned short* As = (unsigned short*)(smem + buf * 18432);
    #pragma unroll
    for (int p = 0; p < 2; ++p) {
      int chunk = (wv * 2 + p) * 64 + lane;
      int row = chunk >> 2, c16 = chunk & 3;
      gl_lds16(wTG + ((size_t)(mb + row)) * 512 + kb + c16 * 8,
               As + (wv * 2 + p) * 512);
    }
  };
  auto bwrite = [&](int buf, const float* xr) {
    unsigned short* Bs = (unsigned short*)(smem + buf * 18432 + 8192);
    unsigned u[8];
    #pragma unroll
    for (int k = 0; k < 16; k += 2) u[k >> 1] = pack2(xr[k], xr[k + 1]);
    uint4* d = (uint4*)&Bs[xn * 40 + xh * 16];
    d[0] = make_uint4(u[0], u[1], u[2], u[3]);
    d[1] = make_uint4(u[4], u[5], u[6], u[7]);
  };
  auto mfma_step = [&](int buf) {
    const unsigned short* As = (const unsigned short*)(smem + buf * 18432);
    const unsigned short* Bs = As + 4096;   // +8192 B
    bf16x8 af[4], bfr[4];
    #pragma unroll
    for (int i = 0; i < 4; ++i)
      af[i] = *(const bf16x8*)&As[(wm + i * 16 + l15) * 32 + l4 * 8];
    #pragma unroll
    for (int j = 0; j < 4; ++j)
      bfr[j] = *(const bf16x8*)&Bs[(wn + j * 16 + l15) * 40 + l4 * 8];
    #pragma unroll
    for (int i = 0; i < 4; ++i)
      #pragma unroll
      for (int j = 0; j < 4; ++j)
        acc[i][j] = __builtin_amdgcn_mfma_f32_16x16x32_bf16(af[i], bfr[j], acc[i][j], 0, 0, 0);
  };

  yload(xrA, 0);
  dmaA(0, 0);
  bwrite(0, xrA);
  yload(xrB, 32);
  __syncthreads();
  for (int t = 0; t < 16; t += 2) {
    // even phase: compute k_t (buf0); stage k_{t+1} (buf1); load k_{t+2}
    dmaA(1, (t + 1) * 32);
    bwrite(1, xrB);
    if (t + 2 < 16) yload(xrA, (t + 2) * 32);
    mfma_step(0);
    __syncthreads();
    // odd phase: compute k_{t+1} (buf1); stage k_{t+2} (buf0); load k_{t+3}
    if (t + 2 < 16) { dmaA(0, (t + 2) * 32); bwrite(0, xrA); }
    if (t + 3 < 16) yload(xrB, (t + 3) * 32);
    mfma_step(1);
    __syncthreads();
  }

  // Fused pooling epilogue: two passes (n-halves = image rows h, h+1).
  const int hloc = wv >> 1;
  #pragma unroll
  for (int pass = 0; pass < 2; ++pass) {
    __syncthreads();
    if (hloc == pass) {
      #pragma unroll
      for (int i = 0; i < 4; ++i)
        #pragma unroll
        for (int j = 0; j < 4; ++j)
          #pragma unroll
          for (int r = 0; r < 4; ++r)
            P[(wm + i * 16 + l4 * 4 + r) * 65 + j * 16 + l15] = acc[i][j][r];
    }
    __syncthreads();
    const int o = tid & 127;
    size_t rbase = (((size_t)(b * 64 + nbt * 2 + pass)) * 18) * 512 + mb + o;
    if (tid < 128) {
      float b0 = -3.4e38f, b1 = b0, b2 = b0, b3 = b0;
      #pragma unroll
      for (int w = 0; w < 64; ++w) {
        float v = P[o * 65 + w];
        b0 = fmaxf(b0, v);
        if (w < 22) b1 = fmaxf(b1, v);
        if (w >= 21 && w < 43) b2 = fmaxf(b2, v);
        if (w >= 42) b3 = fmaxf(b3, v);
      }
      Rbuf[rbase]           = f2bf(b0);
      Rbuf[rbase + 512]     = f2bf(b1);
      Rbuf[rbase + 2 * 512] = f2bf(b2);
      Rbuf[rbase + 3 * 512] = f2bf(b3);
    } else {
      float s6[6], s8[8];
      #pragma unroll
      for (int i = 0; i < 6; ++i) s6[i] = -3.4e38f;
      #pragma unroll
      for (int i = 0; i < 8; ++i) s8[i] = -3.4e38f;
      constexpr int R6S[6] = {0, 10, 21, 32, 42, 53};
      constexpr int R6E[6] = {11, 22, 32, 43, 54, 64};
      #pragma unroll
      for (int w = 0; w < 64; ++w) {
        float v = P[o * 65 + w];
        #pragma unroll
        for (int i = 0; i < 6; ++i)
          if (w >= R6S[i] && w < R6E[i]) s6[i] = fmaxf(s6[i], v);
        s8[w >> 3] = fmaxf(s8[w >> 3], v);
      }
      #pragma unroll
      for (int i = 0; i < 6; ++i) Rbuf[rbase + (size_t)(4 + i) * 512] = f2bf(s6[i]);
      #pragma unroll
      for (int i = 0; i < 8; ++i) Rbuf[rbase + (size_t)(10 + i) * 512] = f2bf(s8[i]);
    }
  }
}

// ---------------------------------------------------------------------------
// K2F: reduce Rbuf over h within each pyramid h-bin -> Pt/Pg [b][128 s][256].
// ---------------------------------------------------------------------------
__global__ __launch_bounds__(256) void k2_pool_final(
    const unsigned short* __restrict__ Rbuf, float* __restrict__ Pt,
    float* __restrict__ Pg)
{
  const int s = blockIdx.x, b = blockIdx.y, tid = threadIdx.x;
  size_t obase = ((size_t)(b * 128) + s) * 256 + tid;
  if (s >= 110) { Pt[obase] = 0.f; Pg[obase] = 0.f; return; }
  int he, wb;
  if (s == 0)      { he = 0; wb = 0; }
  else if (s < 10) { int i = s - 1;  he = 1 + i / 3;  wb = 1 + i % 3; }
  else if (s < 46) { int i = s - 10; he = 4 + i / 6;  wb = 4 + i % 6; }
  else             { int i = s - 46; he = 10 + i / 8; wb = 10 + i % 8; }
  float m0 = -3.4e38f, m1 = -3.4e38f;
  int e = c_RE[he];
  for (int h = c_RS[he]; h < e; ++h) {
    const unsigned short* r = Rbuf + (((size_t)(b * 64 + h)) * 18 + wb) * 512;
    m0 = fmaxf(m0, bf2f(r[tid]));
    m1 = fmaxf(m1, bf2f(r[tid + 256]));
  }
  Pt[obase] = m0;
  Pg[obase] = m1;
}

// ---------------------------------------------------------------------------
// K3 (fused kmat+vmat, blockIdx.z selects):
//  z=0: Kt[b,s,c] = sum_ic w_phi[ic,c]*Pt[b,s,ic] -> hi/lo bf16 split
//  z=1: Vb[b,o,s] = bf16( sum_ic w_mask[o,ic]*Pg[b,s,ic] )
// ---------------------------------------------------------------------------
__global__ __launch_bounds__(256) void k3_fused(
    const float* __restrict__ Pt, const float* __restrict__ Pg,
    const float* __restrict__ w_phi, const float* __restrict__ w_mask,
    unsigned short* __restrict__ Kth, unsigned short* __restrict__ Ktl,
    unsigned short* __restrict__ Vb)
{
  __shared__ __align__(16) char sm3[51200];
  const int tid = threadIdx.x;
  const int tx = tid & 15, ty = tid >> 4;
  const int b = blockIdx.y;
  if (blockIdx.z == 0) {
    const int ct = blockIdx.x;
    const int c0 = tx * 4, s0 = ty * 8;
    float* Ls = (float*)sm3;            // [128][64]
    float* Ws = Ls + 128 * 64;          // [64][68]
    float acc[8][4] = {};
    for (int kc = 0; kc < 256; kc += 64) {
      #pragma unroll
      for (int j = 0; j < 8; ++j) {
        int flat = tid + 256 * j;
        int row = flat >> 4, k4 = (flat & 15) << 2;
        *(float4*)&Ls[row * 64 + k4] =
            *(const float4*)(Pt + ((size_t)(b * 128) + row) * 256 + kc + k4);
      }
      #pragma unroll
      for (int j = 0; j < 4; ++j) {
        int flat = tid + 256 * j;
        int row = flat >> 4, c4 = (flat & 15) << 2;
        *(float4*)&Ws[row * 68 + c4] =
            *(const float4*)(w_phi + (size_t)(kc + row) * 512 + ct * 64 + c4);
      }
      __syncthreads();
      for (int k = 0; k < 64; k += 4) {
        float4 wv[4];
        #pragma unroll
        for (int kk = 0; kk < 4; ++kk) wv[kk] = *(const float4*)&Ws[(k + kk) * 68 + c0];
        #pragma unroll
        for (int i = 0; i < 8; ++i) {
          float4 a = *(const float4*)&Ls[(s0 + i) * 64 + k];
          const float* ap = (const float*)&a;
          #pragma unroll
          for (int kk = 0; kk < 4; ++kk) {
            const float* wp = (const float*)&wv[kk];
            acc[i][0] += ap[kk] * wp[0];
            acc[i][1] += ap[kk] * wp[1];
            acc[i][2] += ap[kk] * wp[2];
            acc[i][3] += ap[kk] * wp[3];
          }
        }
      }
      __syncthreads();
    }
    #pragma unroll
    for (int i = 0; i < 8; ++i) {
      unsigned short hi[4]; float lo[4];
      #pragma unroll
      for (int j = 0; j < 4; ++j) { hi[j] = f2bf(acc[i][j]); lo[j] = acc[i][j] - bf2f(hi[j]); }
      size_t base = ((size_t)(b * 128) + s0 + i) * 512 + ct * 64 + c0;
      uint2 uh; uh.x = (unsigned)hi[0] | ((unsigned)hi[1] << 16);
      uh.y = (unsigned)hi[2] | ((unsigned)hi[3] << 16);
      uint2 ul; ul.x = pack2(lo[0], lo[1]); ul.y = pack2(lo[2], lo[3]);
      *(uint2*)&Kth[base] = uh;
      *(uint2*)&Ktl[base] = ul;
    }
  } else {
    const int ot = blockIdx.x;
    const int o0 = ty * 4;
    float* Ws = (float*)sm3;            // [64][64]
    float* Ps = Ws + 64 * 64;           // [128][68]
    float acc[4][8] = {};
    for (int kc = 0; kc < 256; kc += 64) {
      #pragma unroll
      for (int j = 0; j < 4; ++j) {
        int flat = tid + 256 * j;
        int row = flat >> 4, k4 = (flat & 15) << 2;
        *(float4*)&Ws[row * 64 + k4] =
            *(const float4*)(w_mask + (size_t)(ot * 64 + row) * 256 + kc + k4);
      }
      #pragma unroll
      for (int j = 0; j < 8; ++j) {
        int flat = tid + 256 * j;
        int row = flat >> 4, k4 = (flat & 15) << 2;
        *(float4*)&Ps[row * 68 + k4] =
            *(const float4*)(Pg + ((size_t)(b * 128) + row) * 256 + kc + k4);
      }
      __syncthreads();
      for (int k = 0; k < 64; k += 4) {
        float4 wv[4];
        #pragma unroll
        for (int i = 0; i < 4; ++i) wv[i] = *(const float4*)&Ws[(o0 + i) * 64 + k];
        #pragma unroll
        for (int jj = 0; jj < 8; ++jj) {
          float4 pv = *(const float4*)&Ps[(tx + 16 * jj) * 68 + k];
          const float* pp = (const float*)&pv;
          #pragma unroll
          for (int i = 0; i < 4; ++i) {
            const float* wp = (const float*)&wv[i];
            #pragma unroll
            for (int kk = 0; kk < 4; ++kk) acc[i][jj] += wp[kk] * pp[kk];
          }
        }
      }
      __syncthreads();
    }
    #pragma unroll
    for (int i = 0; i < 4; ++i)
      #pragma unroll
      for (int jj = 0; jj < 8; ++jj)
        Vb[((size_t)(b * 512) + ot * 64 + o0 + i) * 128 + tx + 16 * jj] =
            f2bf(acc[i][jj]);
  }
}

// ---------------------------------------------------------------------------
// K4: scoresT[b,n,s] = sum_c Kt[b,s,c]*x[b,c,n]; Kt hi/lo split (2 MFMAs).
// A via global_load_lds; B from raw x with depth-2 register prefetch (same
// schedule as k1f). Output transposed [n][s] -> float4 stores; epilogue
// emits per-(s, n-tile) softmax partials (max, sum-exp).
// ---------------------------------------------------------------------------
__global__ __launch_bounds__(256) void k4_scores(
    const float* __restrict__ x, const unsigned short* __restrict__ Kth,
    const unsigned short* __restrict__ Ktl, float* __restrict__ scoresT,
    float* __restrict__ pmax_g, float* __restrict__ psum_g)
{
  const int tid = threadIdx.x;
  const int ntile = blockIdx.x;
  const int nb = ntile * 128;
  const int b = blockIdx.y;
  const int lane = tid & 63, wv = tid >> 6;
  const int wm = (wv & 1) * 64, wn = (wv >> 1) * 64;
  const int l15 = lane & 15, l4 = lane >> 4;
  // per buffer: Ah 8192 | Al 8192 | Bs [128][40] 10240 -> 26624 B
  __shared__ __align__(16) char smem4[2 * 26624];
  __shared__ float SmP[256], SsP[256];

  const int xn = tid & 127, xh = tid >> 7;
  const float* xcol = x + ((size_t)(b * 512 + xh * 16)) * 4096 + nb + xn;

  f32x4 acc[4][4];
  #pragma unroll
  for (int i = 0; i < 4; ++i)
    #pragma unroll
    for (int j = 0; j < 4; ++j) acc[i][j] = f32x4{0.f, 0.f, 0.f, 0.f};

  float xrA[16], xrB[16];
  auto xload = [&](float* xr, int kb) {
    const float* p = xcol + (size_t)kb * 4096;
    #pragma unroll
    for (int k = 0; k < 16; ++k) xr[k] = p[(size_t)k * 4096];
  };
  auto dmaA = [&](int buf, int kb) {
    unsigned short* Ah = (unsigned short*)(smem4 + buf * 26624);
    unsigned short* Al = Ah + 4096;
    #pragma unroll
    for (int p = 0; p < 2; ++p) {
      int chunk = (wv * 2 + p) * 64 + lane;
      int row = chunk >> 2, c16 = chunk & 3;
      size_t g = ((size_t)(b * 128) + row) * 512 + kb + c16 * 8;
      gl_lds16(Kth + g, Ah + (wv * 2 + p) * 512);
      gl_lds16(Ktl + g, Al + (wv * 2 + p) * 512);
    }
  };
  auto bwrite = [&](int buf, const float* xr) {
    unsigned short* Bs = (unsigned short*)(smem4 + buf * 26624 + 16384);
    unsigned u[8];
    #pragma unroll
    for (int k = 0; k < 16; k += 2) u[k >> 1] = pack2(xr[k], xr[k + 1]);
    uint4* d = (uint4*)&Bs[xn * 40 + xh * 16];
    d[0] = make_uint4(u[0], u[1], u[2], u[3]);
    d[1] = make_uint4(u[4], u[5], u[6], u[7]);
  };
  auto mfma_step = [&](int buf) {
    const unsigned short* Ah = (const unsigned short*)(smem4 + buf * 26624);
    const unsigned short* Al = Ah + 4096;
    const unsigned short* Bs = Al + 4096;
    bf16x8 ah[4], al[4], bfr[4];
    #pragma unroll
    for (int i = 0; i < 4; ++i) {
      ah[i] = *(const bf16x8*)&Ah[(wm + i * 16 + l15) * 32 + l4 * 8];
      al[i] = *(const bf16x8*)&Al[(wm + i * 16 + l15) * 32 + l4 * 8];
    }
    #pragma unroll
    for (int j = 0; j < 4; ++j)
      bfr[j] = *(const bf16x8*)&Bs[(wn + j * 16 + l15) * 40 + l4 * 8];
    #pragma unroll
    for (int i = 0; i < 4; ++i)
      #pragma unroll
      for (int j = 0; j < 4; ++j) {
        acc[i][j] = __builtin_amdgcn_mfma_f32_16x16x32_bf16(ah[i], bfr[j], acc[i][j], 0, 0, 0);
        acc[i][j] = __builtin_amdgcn_mfma_f32_16x16x32_bf16(al[i], bfr[j], acc[i][j], 0, 0, 0);
      }
  };

  xload(xrA, 0);
  dmaA(0, 0);
  bwrite(0, xrA);
  xload(xrB, 32);
  __syncthreads();
  for (int t = 0; t < 16; t += 2) {
    dmaA(1, (t + 1) * 32);
    bwrite(1, xrB);
    if (t + 2 < 16) xload(xrA, (t + 2) * 32);
    mfma_step(0);
    __syncthreads();
    if (t + 2 < 16) { dmaA(0, (t + 2) * 32); bwrite(0, xrA); }
    if (t + 3 < 16) xload(xrB, (t + 3) * 32);
    mfma_step(1);
    __syncthreads();
  }

  // scoresT store: n row = nb+wn+j*16+l15, s base = wm+i*16+l4*4 (float4 in s)
  #pragma unroll
  for (int i = 0; i < 4; ++i)
    #pragma unroll
    for (int j = 0; j < 4; ++j)
      *(float4*)(scoresT + ((size_t)(b * 4096) + nb + wn + j * 16 + l15) * 128 +
                 wm + i * 16 + l4 * 4) = *(float4*)&acc[i][j];

  // Softmax partials for this 128s x 128n tile.
  const int nh = wn >> 6;
  float cm[4][4];
  #pragma unroll
  for (int i = 0; i < 4; ++i)
    #pragma unroll
    for (int r = 0; r < 4; ++r) {
      float v = fmaxf(fmaxf(acc[i][0][r], acc[i][1][r]),
                      fmaxf(acc[i][2][r], acc[i][3][r]));
      v = fmaxf(v, __shfl_xor(v, 1));
      v = fmaxf(v, __shfl_xor(v, 2));
      v = fmaxf(v, __shfl_xor(v, 4));
      v = fmaxf(v, __shfl_xor(v, 8));
      if (l15 == 0) SmP[(wm + i * 16 + l4 * 4 + r) * 2 + nh] = v;
    }
  __syncthreads();
  #pragma unroll
  for (int i = 0; i < 4; ++i)
    #pragma unroll
    for (int r = 0; r < 4; ++r) {
      int s = wm + i * 16 + l4 * 4 + r;
      cm[i][r] = fmaxf(SmP[s * 2], SmP[s * 2 + 1]);
    }
  #pragma unroll
  for (int i = 0; i < 4; ++i)
    #pragma unroll
    for (int r = 0; r < 4; ++r) {
      float s0 = __expf(acc[i][0][r] - cm[i][r]) + __expf(acc[i][1][r] - cm[i][r]) +
                 __expf(acc[i][2][r] - cm[i][r]) + __expf(acc[i][3][r] - cm[i][r]);
      s0 += __shfl_xor(s0, 1);
      s0 += __shfl_xor(s0, 2);
      s0 += __shfl_xor(s0, 4);
      s0 += __shfl_xor(s0, 8);
      if (l15 == 0) SsP[(wm + i * 16 + l4 * 4 + r) * 2 + nh] = s0;
    }
  __syncthreads();
  if (tid < 128) {
    size_t pidx = ((size_t)(b * 128) + tid) * 32 + ntile;
    pmax_g[pidx] = fmaxf(SmP[tid * 2], SmP[tid * 2 + 1]);
    psum_g[pidx] = SsP[tid * 2] + SsP[tid * 2 + 1];
  }
}

// ---------------------------------------------------------------------------
// K5E: combine per-tile partials -> (m, 1/sum) per (b,s), then stream
// Eb[b,n,s] = bf16( exp(scoresT[b,n,s]-m[s]) * linv[s] ).
// ---------------------------------------------------------------------------
__global__ __launch_bounds__(256) void k5e_exp(
    const float* __restrict__ scoresT, const float* __restrict__ pmax_g,
    const float* __restrict__ psum_g, unsigned short* __restrict__ Eb)
{
  const int b = blockIdx.y, tid = threadIdx.x;
  __shared__ float sm[128], sl[128];
  if (tid < 128) {
    float M = 0.f, linv = 0.f;
    if (tid < 110) {
      const float* pm = pmax_g + ((size_t)(b * 128) + tid) * 32;
      const float* ps = psum_g + ((size_t)(b * 128) + tid) * 32;
      M = -3.4e38f;
      #pragma unroll
      for (int t = 0; t < 32; ++t) M = fmaxf(M, pm[t]);
      float S = 0.f;
      #pragma unroll
      for (int t = 0; t < 32; ++t) S += ps[t] * __expf(pm[t] - M);
      linv = 1.f / S;
    }
    sm[tid] = M; sl[tid] = linv;
  }
  __syncthreads();
  const size_t base = (size_t)b * 4096 * 128;
  #pragma unroll
  for (int j = 0; j < 8; ++j) {
    int chunk = blockIdx.x * 2048 + j * 256 + tid;   // float4 id within b
    int sc = (chunk & 31) * 4;
    float4 v = *(const float4*)(scoresT + base + (size_t)chunk * 4);
    float e0 = __expf(v.x - sm[sc])     * sl[sc];
    float e1 = __expf(v.y - sm[sc + 1]) * sl[sc + 1];
    float e2 = __expf(v.z - sm[sc + 2]) * sl[sc + 2];
    float e3 = __expf(v.w - sm[sc + 3]) * sl[sc + 3];
    uint2 u; u.x = pack2(e0, e1); u.y = pack2(e2, e3);
    *(uint2*)(Eb + base + (size_t)chunk * 4) = u;
  }
}

// ---------------------------------------------------------------------------
// K6: out[b,o,n] = sum_s Vb[b,o,s] * Eb[b,n,s] + x[b,o,n]
// Whole K=128 staged at once (ONE barrier); x prefetched into VGPRs while
// the LDS-DMA is in flight. XCD-chunked tile swizzle: the 4 mb-blocks
// sharing an Eb n-panel co-locate on one XCD (L2 reuse).
// ---------------------------------------------------------------------------
__global__ __launch_bounds__(256) void k6_out(
    const unsigned short* __restrict__ Eb, const unsigned short* __restrict__ Vb,
    const float* __restrict__ x, float* __restrict__ out)
{
  const int tid = threadIdx.x;
  const int id = blockIdx.x;
  const int tile = (id & 7) * 16 + (id >> 3);   // XCD-chunked, bijective
  const int mb = (tile & 3) * 128;
  const int nb = (tile >> 2) * 128;
  const int b = blockIdx.y;
  const int lane = tid & 63, wv = tid >> 6;
  const int wm = (wv & 1) * 64, wn = (wv >> 1) * 64;
  const int l15 = lane & 15, l4 = lane >> 4;
  __shared__ __align__(16) unsigned short SA[4][4096];   // 32 KB
  __shared__ __align__(16) unsigned short SB[4][4096];   // 32 KB

  #pragma unroll
  for (int h = 0; h < 4; ++h)
    #pragma unroll
    for (int p = 0; p < 2; ++p) {
      int chunk = (wv * 2 + p) * 64 + lane;
      int row = chunk >> 2, c16 = chunk & 3;
      gl_lds16(Vb + ((size_t)(b * 512) + mb + row) * 128 + h * 32 + c16 * 8,
               &SA[h][(wv * 2 + p) * 512]);
      gl_lds16(Eb + ((size_t)(b * 4096) + nb + row) * 128 + h * 32 + c16 * 8,
               &SB[h][(wv * 2 + p) * 512]);
    }

  float xr[4][4][4];
  #pragma unroll
  for (int i = 0; i < 4; ++i)
    #pragma unroll
    for (int j = 0; j < 4; ++j)
      #pragma unroll
      for (int r = 0; r < 4; ++r)
        xr[i][j][r] = x[((size_t)(b * 512) + mb + wm + i * 16 + l4 * 4 + r) * 4096 +
                        nb + wn + j * 16 + l15];

  f32x4 acc[4][4];
  #pragma unroll
  for (int i = 0; i < 4; ++i)
    #pragma unroll
    for (int j = 0; j < 4; ++j) acc[i][j] = f32x4{0.f, 0.f, 0.f, 0.f};

  __syncthreads();
  #pragma unroll
  for (int h = 0; h < 4; ++h) {
    bf16x8 af[4], bfr[4];
    #pragma unroll
    for (int i = 0; i < 4; ++i)
      af[i] = *(const bf16x8*)&SA[h][(wm + i * 16 + l15) * 32 + l4 * 8];
    #pragma unroll
    for (int j = 0; j < 4; ++j)
      bfr[j] = *(const bf16x8*)&SB[h][(wn + j * 16 + l15) * 32 + l4 * 8];
    #pragma unroll
    for (int i = 0; i < 4; ++i)
      #pragma unroll
      for (int j = 0; j < 4; ++j)
        acc[i][j] = __builtin_amdgcn_mfma_f32_16x16x32_bf16(af[i], bfr[j], acc[i][j], 0, 0, 0);
  }
  #pragma unroll
  for (int i = 0; i < 4; ++i)
    #pragma unroll
    for (int j = 0; j < 4; ++j)
      #pragma unroll
      for (int r = 0; r < 4; ++r) {
        int o = mb + wm + i * 16 + l4 * 4 + r;
        size_t idx = ((size_t)(b * 512) + o) * 4096 + nb + wn + j * 16 + l15;
        out[idx] = acc[i][j][r] + xr[i][j][r];
      }
}

// ---------------------------------------------------------------------------
extern "C" void kernel_launch(void* const* d_in, const int* in_sizes, int n_in,
                              void* d_out, int out_size, void* d_ws, size_t ws_size,
                              hipStream_t stream)
{
  (void)in_sizes; (void)n_in; (void)out_size; (void)ws_size;
  const float* x       = (const float*)d_in[0];
  const float* y       = (const float*)d_in[1];
  const float* w_phi   = (const float*)d_in[2];
  const float* w_theta = (const float*)d_in[3];
  const float* w_g     = (const float*)d_in[4];
  const float* w_mask  = (const float*)d_in[5];
  float* out = (float*)d_out;

  // Workspace: 130,039,808 B total (region A now unused — no pre-transposes).
  // Region B (54525952): Rbuf (18.9MB) -> scoresT (33.5MB, after k2) |
  //   Eb (16.8MB) | tail: wTG (512KB, pw->k1f) / Vb (2MB, k3->k6) +
  //   pmax/psum (512KB, k4->k5e).
  // Region C (8404992): Pt, Pg, Kth, Ktl.
  char* ws = (char*)d_ws;
  char* B0 = ws + 67108864;
  unsigned short* Rbuf = (unsigned short*)B0;                 // 18874368 B
  float* scoresT = (float*)B0;                                // 33554432 B (after k2)
  unsigned short* Eb = (unsigned short*)(B0 + 33554432);      // 16777216 B
  unsigned short* wTG = (unsigned short*)(B0 + 50331648);     // 524288 B (pw->k1f)
  unsigned short* Vb  = (unsigned short*)(B0 + 50331648);     // 2097152 B (k3->k6)
  float* pmax_g = (float*)(B0 + 52428800);                    // 262144 B (k4->k5e)
  float* psum_g = (float*)(B0 + 52690944);                    // 262144 B (k4->k5e)
  char* C0 = B0 + 54525952;
  float* Pt = (float*)C0;                                     // 2097152
  float* Pg = (float*)(C0 + 2097152);                         // 2097152
  unsigned short* Kth = (unsigned short*)(C0 + 4194304);      // 2097152
  unsigned short* Ktl = (unsigned short*)(C0 + 6291456);      // 2097152

  pw_conv<<<dim3(128), 256, 0, stream>>>(w_theta, w_g, wTG);
  k1f_conv_pool<<<dim3(128, 16), 256, 0, stream>>>(y, wTG, Rbuf);
  k2_pool_final<<<dim3(128, 16), 256, 0, stream>>>(Rbuf, Pt, Pg);
  k3_fused<<<dim3(8, 16, 2), 256, 0, stream>>>(Pt, Pg, w_phi, w_mask, Kth, Ktl, Vb);
  k4_scores<<<dim3(32, 16), 256, 0, stream>>>(x, Kth, Ktl, scoresT, pmax_g, psum_g);
  k5e_exp<<<dim3(64, 16), 256, 0, stream>>>(scoresT, pmax_g, psum_g, Eb);
  k6_out<<<dim3(128, 16), 256, 0, stream>>>(Eb, Vb, x, out);
}